// Round 1
// baseline (4901.901 us; speedup 1.0000x reference)
//
#include <hip/hip_runtime.h>

#define D 128
constexpr float EPS = 1e-5f;

// ---------- edge scalar weight: mean over 4 features ----------
__global__ void k_edge_ws(const float4* __restrict__ w, float* __restrict__ ws, int E) {
  int e = blockIdx.x * 256 + threadIdx.x;
  if (e < E) {
    float4 v = w[e];
    ws[e] = (v.x + v.y + v.z + v.w) * 0.25f;
  }
}

// ---------- unweighted degrees (atomic count) ----------
__global__ void k_degree(const int* __restrict__ src, const int* __restrict__ dst,
                         float* __restrict__ outd, float* __restrict__ ind, int E) {
  int e = blockIdx.x * 256 + threadIdx.x;
  if (e < E) {
    atomicAdd(&outd[src[e]], 1.0f);
    atomicAdd(&ind[dst[e]], 1.0f);
  }
}

// ---------- deg -> rsqrt(clamp(deg,1)) in place ----------
__global__ void k_norm(float* __restrict__ outd, float* __restrict__ ind, int N) {
  int n = blockIdx.x * 256 + threadIdx.x;
  if (n < N) {
    outd[n] = rsqrtf(fmaxf(outd[n], 1.0f));
    ind[n]  = rsqrtf(fmaxf(ind[n], 1.0f));
  }
}

// ---------- scatter: agg[dst] += h[src]*out_norm[src]*ws[e]  (32 threads/edge, float4 each) ----------
__global__ void k_scatter(const float* __restrict__ h, const int* __restrict__ src,
                          const int* __restrict__ dst, const float* __restrict__ ws,
                          const float* __restrict__ outn, float* __restrict__ agg, int E) {
  int idx = blockIdx.x * 256 + threadIdx.x;
  int e = idx >> 5, c = idx & 31;
  if (e >= E) return;
  int s = src[e], d = dst[e];
  float coef = ws[e] * outn[s];
  float4 v = ((const float4*)(h + (size_t)s * D))[c];
  float* p = agg + (size_t)d * D + c * 4;
  atomicAdd(p + 0, v.x * coef);
  atomicAdd(p + 1, v.y * coef);
  atomicAdd(p + 2, v.z * coef);
  atomicAdd(p + 3, v.w * coef);
}

// ---------- fused: out_row = LN(relu((agg_row*in_norm) @ W)) ; one wave per row ----------
__global__ __launch_bounds__(256) void k_gemm_ln(
    const float* __restrict__ agg, const float* __restrict__ innorm,
    const float* __restrict__ W, const float* __restrict__ g, const float* __restrict__ bta,
    float* __restrict__ out, int N, int do_ln) {
  __shared__ float Wl[D * D];  // 64 KiB
  for (int i = threadIdx.x; i < D * D / 4; i += 256)
    ((float4*)Wl)[i] = ((const float4*)W)[i];
  __syncthreads();
  int lane = threadIdx.x & 63, wv = threadIdx.x >> 6;
  float gv0 = 1.f, gv1 = 1.f, bv0 = 0.f, bv1 = 0.f;
  if (do_ln) { gv0 = g[lane]; gv1 = g[lane + 64]; bv0 = bta[lane]; bv1 = bta[lane + 64]; }
  int nw = gridDim.x * 4;
  for (int r = blockIdx.x * 4 + wv; r < N; r += nw) {
    float sc = innorm[r];
    float rv0 = agg[(size_t)r * D + lane] * sc;
    float rv1 = agg[(size_t)r * D + 64 + lane] * sc;
    float acc0 = 0.f, acc1 = 0.f;
#pragma unroll
    for (int k = 0; k < 64; ++k) {
      float v = __shfl(rv0, k);
      acc0 = fmaf(v, Wl[k * D + lane], acc0);
      acc1 = fmaf(v, Wl[k * D + 64 + lane], acc1);
    }
#pragma unroll
    for (int k = 0; k < 64; ++k) {
      float v = __shfl(rv1, k);
      acc0 = fmaf(v, Wl[(k + 64) * D + lane], acc0);
      acc1 = fmaf(v, Wl[(k + 64) * D + 64 + lane], acc1);
    }
    if (do_ln) {
      acc0 = fmaxf(acc0, 0.f);
      acc1 = fmaxf(acc1, 0.f);
      float s = acc0 + acc1;
#pragma unroll
      for (int off = 32; off; off >>= 1) s += __shfl_xor(s, off);
      float mu = s * (1.0f / D);
      float d0 = acc0 - mu, d1 = acc1 - mu;
      float vs = d0 * d0 + d1 * d1;
#pragma unroll
      for (int off = 32; off; off >>= 1) vs += __shfl_xor(vs, off);
      float rs = rsqrtf(vs * (1.0f / D) + EPS);
      acc0 = d0 * rs * gv0 + bv0;
      acc1 = d1 * rs * gv1 + bv1;
    }
    out[(size_t)r * D + lane] = acc0;
    out[(size_t)r * D + 64 + lane] = acc1;
  }
}

// ---------- readout: one block per graph, binary search sorted graph_ids ----------
__global__ void k_readout(const float* __restrict__ h, const int* __restrict__ gid,
                          float* __restrict__ out, int N) {
  int b = blockIdx.x;
  int t = threadIdx.x;  // 128 threads
  int lo = 0, hi = N;
  while (lo < hi) { int m = (lo + hi) >> 1; if (gid[m] < b) lo = m + 1; else hi = m; }
  int start = lo;
  int lo2 = start, hi2 = N;
  while (lo2 < hi2) { int m = (lo2 + hi2) >> 1; if (gid[m] < b + 1) lo2 = m + 1; else hi2 = m; }
  int end = lo2;
  float acc = 0.f;
  for (int n = start; n < end; ++n) acc += h[(size_t)n * D + t];
  out[b * D + t] = acc;
}

extern "C" void kernel_launch(void* const* d_in, const int* in_sizes, int n_in,
                              void* d_out, int out_size, void* d_ws, size_t ws_size,
                              hipStream_t stream) {
  const float* x    = (const float*)d_in[0];
  const float* w    = (const float*)d_in[1];
  const float* W1   = (const float*)d_in[2];
  const float* W2   = (const float*)d_in[3];
  const float* W3   = (const float*)d_in[4];
  const float* ln1g = (const float*)d_in[5];
  const float* ln1b = (const float*)d_in[6];
  const float* ln2g = (const float*)d_in[7];
  const float* ln2b = (const float*)d_in[8];
  const int* src = (const int*)d_in[9];
  const int* dst = (const int*)d_in[10];
  const int* gid = (const int*)d_in[11];
  const int N = in_sizes[0] / D;
  const int E = in_sizes[9];
  const int B = out_size / D;
  float* outp = (float*)d_out;

  // workspace layout
  float* A    = (float*)d_ws;             // [N*D] agg buffer
  float* Bb   = A + (size_t)N * D;        // [N*D] h buffer
  float* wsE  = Bb + (size_t)N * D;       // [E] edge scalar weights
  float* outn = wsE + E;                  // [N] out_norm
  float* innm = outn + N;                 // [N] in_norm (contiguous with outn)

  const int eb = (E + 255) / 256;
  const int nb = (N + 255) / 256;
  const int sb = (int)(((size_t)E * 32 + 255) / 256);

  // preprocessing
  hipMemsetAsync(outn, 0, sizeof(float) * 2 * (size_t)N, stream);
  k_edge_ws<<<eb, 256, 0, stream>>>((const float4*)w, wsE, E);
  k_degree<<<eb, 256, 0, stream>>>(src, dst, outn, innm, E);
  k_norm<<<nb, 256, 0, stream>>>(outn, innm, N);

  // layer 1: x -> A(agg) -> Bb(h1)
  hipMemsetAsync(A, 0, sizeof(float) * (size_t)N * D, stream);
  k_scatter<<<sb, 256, 0, stream>>>(x, src, dst, wsE, outn, A, E);
  k_gemm_ln<<<512, 256, 0, stream>>>(A, innm, W1, ln1g, ln1b, Bb, N, 1);

  // layer 2: Bb -> A(agg) -> Bb(h2)
  hipMemsetAsync(A, 0, sizeof(float) * (size_t)N * D, stream);
  k_scatter<<<sb, 256, 0, stream>>>(Bb, src, dst, wsE, outn, A, E);
  k_gemm_ln<<<512, 256, 0, stream>>>(A, innm, W2, ln2g, ln2b, Bb, N, 1);

  // layer 3: Bb -> A(agg) -> Bb(h3), no relu/ln
  hipMemsetAsync(A, 0, sizeof(float) * (size_t)N * D, stream);
  k_scatter<<<sb, 256, 0, stream>>>(Bb, src, dst, wsE, outn, A, E);
  k_gemm_ln<<<512, 256, 0, stream>>>(A, innm, W3, nullptr, nullptr, Bb, N, 0);

  // readout
  k_readout<<<B, D, 0, stream>>>(Bb, gid, outp, N);
}

// Round 2
// 1136.900 us; speedup vs baseline: 4.3116x; 4.3116x over previous
//
#include <hip/hip_runtime.h>

#define D 128
constexpr float EPS = 1e-5f;

// ---------- int degree counts (out by src, in by dst) ----------
__global__ void k_count(const int* __restrict__ src, const int* __restrict__ dst,
                        int* __restrict__ ocnt, int* __restrict__ icnt, int E) {
  int e = blockIdx.x * 256 + threadIdx.x;
  if (e < E) {
    atomicAdd(&ocnt[src[e]], 1);
    atomicAdd(&icnt[dst[e]], 1);
  }
}

// ---------- norms from int degrees ----------
__global__ void k_norm(const int* __restrict__ ocnt, const int* __restrict__ icnt,
                       float* __restrict__ outn, float* __restrict__ innm, int N) {
  int n = blockIdx.x * 256 + threadIdx.x;
  if (n < N) {
    outn[n] = rsqrtf(fmaxf((float)ocnt[n], 1.0f));
    innm[n] = rsqrtf(fmaxf((float)icnt[n], 1.0f));
  }
}

// ---------- single-block exclusive scan of icnt -> rowptr[N+1] ----------
__global__ __launch_bounds__(1024) void k_scan(const int* __restrict__ cnt,
                                               int* __restrict__ rowptr, int N) {
  __shared__ int part[1024];
  int t = threadIdx.x;
  int chunk = (N + 1023) / 1024;
  int beg = t * chunk, end = min(beg + chunk, N);
  int s = 0;
  for (int i = beg; i < end; ++i) s += cnt[i];
  part[t] = s;
  __syncthreads();
  for (int off = 1; off < 1024; off <<= 1) {
    int v = (t >= off) ? part[t - off] : 0;
    __syncthreads();
    part[t] += v;
    __syncthreads();
  }
  int excl = (t == 0) ? 0 : part[t - 1];
  for (int i = beg; i < end; ++i) { rowptr[i] = excl; excl += cnt[i]; }
  if (t == 0) rowptr[N] = part[1023];
}

// ---------- place edges into CSR order; precompute coef = mean(w)*out_norm[src] ----------
__global__ void k_place(const int* __restrict__ src, const int* __restrict__ dst,
                        const float4* __restrict__ w, const float* __restrict__ outn,
                        const int* __restrict__ rowptr, int* __restrict__ cursor,
                        int* __restrict__ src_p, float* __restrict__ coef_p, int E) {
  int e = blockIdx.x * 256 + threadIdx.x;
  if (e >= E) return;
  int d = dst[e];
  int p = rowptr[d] + atomicAdd(&cursor[d], 1);
  int s = src[e];
  float4 v = w[e];
  src_p[p] = s;
  coef_p[p] = (v.x + v.y + v.z + v.w) * 0.25f * outn[s];
}

// ---------- gather: agg[n] = sum_{j in row n} coef_p[j] * h[src_p[j]]  (32 lanes/node, float4) ----------
__global__ __launch_bounds__(256) void k_gather(
    const float* __restrict__ h, const int* __restrict__ rowptr,
    const int* __restrict__ src_p, const float* __restrict__ coef_p,
    float* __restrict__ agg, int N) {
  int idx = blockIdx.x * 256 + threadIdx.x;
  int n = idx >> 5, c = idx & 31;
  if (n >= N) return;
  int beg = rowptr[n], end = rowptr[n + 1];
  float ax = 0.f, ay = 0.f, az = 0.f, aw = 0.f;
  for (int j = beg; j < end; ++j) {
    int s = src_p[j];
    float cf = coef_p[j];
    float4 v = ((const float4*)(h + (size_t)s * D))[c];
    ax = fmaf(v.x, cf, ax);
    ay = fmaf(v.y, cf, ay);
    az = fmaf(v.z, cf, az);
    aw = fmaf(v.w, cf, aw);
  }
  float4 r; r.x = ax; r.y = ay; r.z = az; r.w = aw;
  ((float4*)(agg + (size_t)n * D))[c] = r;
}

// ---------- fused: out_row = LN(relu((agg_row*in_norm) @ W)) ; one wave per row ----------
__global__ __launch_bounds__(256) void k_gemm_ln(
    const float* __restrict__ agg, const float* __restrict__ innorm,
    const float* __restrict__ W, const float* __restrict__ g, const float* __restrict__ bta,
    float* __restrict__ out, int N, int do_ln) {
  __shared__ float Wl[D * D];  // 64 KiB
  for (int i = threadIdx.x; i < D * D / 4; i += 256)
    ((float4*)Wl)[i] = ((const float4*)W)[i];
  __syncthreads();
  int lane = threadIdx.x & 63, wv = threadIdx.x >> 6;
  float gv0 = 1.f, gv1 = 1.f, bv0 = 0.f, bv1 = 0.f;
  if (do_ln) { gv0 = g[lane]; gv1 = g[lane + 64]; bv0 = bta[lane]; bv1 = bta[lane + 64]; }
  int nw = gridDim.x * 4;
  for (int r = blockIdx.x * 4 + wv; r < N; r += nw) {
    float sc = innorm[r];
    float rv0 = agg[(size_t)r * D + lane] * sc;
    float rv1 = agg[(size_t)r * D + 64 + lane] * sc;
    float acc0 = 0.f, acc1 = 0.f;
#pragma unroll
    for (int k = 0; k < 64; ++k) {
      float v = __shfl(rv0, k);
      acc0 = fmaf(v, Wl[k * D + lane], acc0);
      acc1 = fmaf(v, Wl[k * D + 64 + lane], acc1);
    }
#pragma unroll
    for (int k = 0; k < 64; ++k) {
      float v = __shfl(rv1, k);
      acc0 = fmaf(v, Wl[(k + 64) * D + lane], acc0);
      acc1 = fmaf(v, Wl[(k + 64) * D + 64 + lane], acc1);
    }
    if (do_ln) {
      acc0 = fmaxf(acc0, 0.f);
      acc1 = fmaxf(acc1, 0.f);
      float s = acc0 + acc1;
#pragma unroll
      for (int off = 32; off; off >>= 1) s += __shfl_xor(s, off);
      float mu = s * (1.0f / D);
      float d0 = acc0 - mu, d1 = acc1 - mu;
      float vs = d0 * d0 + d1 * d1;
#pragma unroll
      for (int off = 32; off; off >>= 1) vs += __shfl_xor(vs, off);
      float rs = rsqrtf(vs * (1.0f / D) + EPS);
      acc0 = d0 * rs * gv0 + bv0;
      acc1 = d1 * rs * gv1 + bv1;
    }
    out[(size_t)r * D + lane] = acc0;
    out[(size_t)r * D + 64 + lane] = acc1;
  }
}

// ---------- readout: one block per graph, binary search sorted graph_ids ----------
__global__ void k_readout(const float* __restrict__ h, const int* __restrict__ gid,
                          float* __restrict__ out, int N) {
  int b = blockIdx.x;
  int t = threadIdx.x;  // 128 threads
  int lo = 0, hi = N;
  while (lo < hi) { int m = (lo + hi) >> 1; if (gid[m] < b) lo = m + 1; else hi = m; }
  int start = lo;
  int lo2 = start, hi2 = N;
  while (lo2 < hi2) { int m = (lo2 + hi2) >> 1; if (gid[m] < b + 1) lo2 = m + 1; else hi2 = m; }
  int end = lo2;
  float acc = 0.f;
  for (int n = start; n < end; ++n) acc += h[(size_t)n * D + t];
  out[b * D + t] = acc;
}

extern "C" void kernel_launch(void* const* d_in, const int* in_sizes, int n_in,
                              void* d_out, int out_size, void* d_ws, size_t ws_size,
                              hipStream_t stream) {
  const float* x    = (const float*)d_in[0];
  const float* w    = (const float*)d_in[1];
  const float* W1   = (const float*)d_in[2];
  const float* W2   = (const float*)d_in[3];
  const float* W3   = (const float*)d_in[4];
  const float* ln1g = (const float*)d_in[5];
  const float* ln1b = (const float*)d_in[6];
  const float* ln2g = (const float*)d_in[7];
  const float* ln2b = (const float*)d_in[8];
  const int* src = (const int*)d_in[9];
  const int* dst = (const int*)d_in[10];
  const int* gid = (const int*)d_in[11];
  const int N = in_sizes[0] / D;
  const int E = in_sizes[9];
  const int B = out_size / D;
  float* outp = (float*)d_out;

  // workspace layout (floats/ints are both 4B)
  float* A     = (float*)d_ws;               // [N*D] agg
  float* Bb    = A + (size_t)N * D;          // [N*D] h
  float* outn  = Bb + (size_t)N * D;         // [N]
  float* innm  = outn + N;                   // [N]
  int*   ocnt  = (int*)(innm + N);           // [N]
  int*   icnt  = ocnt + N;                   // [N]
  int*   cursor= icnt + N;                   // [N]   (memset with ocnt/icnt: contiguous 3N)
  int*   rowptr= cursor + N;                 // [N+1]
  int*   src_p = rowptr + N + 1;             // [E]
  float* coef_p= (float*)(src_p + E);        // [E]

  const int eb = (E + 255) / 256;
  const int nb = (N + 255) / 256;
  const int gb = (int)(((size_t)N * 32 + 255) / 256);

  // ---- CSR build (once per call) ----
  hipMemsetAsync(ocnt, 0, sizeof(int) * 3 * (size_t)N, stream);  // ocnt, icnt, cursor
  k_count<<<eb, 256, 0, stream>>>(src, dst, ocnt, icnt, E);
  k_norm<<<nb, 256, 0, stream>>>(ocnt, icnt, outn, innm, N);
  k_scan<<<1, 1024, 0, stream>>>(icnt, rowptr, N);
  k_place<<<eb, 256, 0, stream>>>(src, dst, (const float4*)w, outn, rowptr, cursor,
                                  src_p, coef_p, E);

  // ---- layer 1: x -> A -> Bb ----
  k_gather<<<gb, 256, 0, stream>>>(x, rowptr, src_p, coef_p, A, N);
  k_gemm_ln<<<512, 256, 0, stream>>>(A, innm, W1, ln1g, ln1b, Bb, N, 1);

  // ---- layer 2: Bb -> A -> Bb ----
  k_gather<<<gb, 256, 0, stream>>>(Bb, rowptr, src_p, coef_p, A, N);
  k_gemm_ln<<<512, 256, 0, stream>>>(A, innm, W2, ln2g, ln2b, Bb, N, 1);

  // ---- layer 3: Bb -> A -> Bb (no relu/ln) ----
  k_gather<<<gb, 256, 0, stream>>>(Bb, rowptr, src_p, coef_p, A, N);
  k_gemm_ln<<<512, 256, 0, stream>>>(A, innm, W3, nullptr, nullptr, Bb, N, 0);

  // ---- readout ----
  k_readout<<<B, D, 0, stream>>>(Bb, gid, outp, N);
}

// Round 3
// 708.923 us; speedup vs baseline: 6.9146x; 1.6037x over previous
//
#include <hip/hip_runtime.h>

#define D 128
#define BM 64  // rows per k_gemm block (4 waves x 16 rows)
constexpr float EPS = 1e-5f;

// ---------- int degree counts (out by src, in by dst) ----------
__global__ void k_count(const int* __restrict__ src, const int* __restrict__ dst,
                        int* __restrict__ ocnt, int* __restrict__ icnt, int E) {
  int e = blockIdx.x * 256 + threadIdx.x;
  if (e < E) {
    atomicAdd(&ocnt[src[e]], 1);
    atomicAdd(&icnt[dst[e]], 1);
  }
}

// ---------- norms from int degrees ----------
__global__ void k_norm(const int* __restrict__ ocnt, const int* __restrict__ icnt,
                       float* __restrict__ outn, float* __restrict__ innm, int N) {
  int n = blockIdx.x * 256 + threadIdx.x;
  if (n < N) {
    outn[n] = rsqrtf(fmaxf((float)ocnt[n], 1.0f));
    innm[n] = rsqrtf(fmaxf((float)icnt[n], 1.0f));
  }
}

// ---------- single-block exclusive scan of icnt -> rowptr[N+1] ----------
__global__ __launch_bounds__(1024) void k_scan(const int* __restrict__ cnt,
                                               int* __restrict__ rowptr, int N) {
  __shared__ int part[1024];
  int t = threadIdx.x;
  int chunk = (N + 1023) / 1024;
  int beg = t * chunk, end = min(beg + chunk, N);
  int s = 0;
  for (int i = beg; i < end; ++i) s += cnt[i];
  part[t] = s;
  __syncthreads();
  for (int off = 1; off < 1024; off <<= 1) {
    int v = (t >= off) ? part[t - off] : 0;
    __syncthreads();
    part[t] += v;
    __syncthreads();
  }
  int excl = (t == 0) ? 0 : part[t - 1];
  for (int i = beg; i < end; ++i) { rowptr[i] = excl; excl += cnt[i]; }
  if (t == 0) rowptr[N] = part[1023];
}

// ---------- place edges into CSR order; precompute coef = mean(w)*out_norm[src] ----------
__global__ void k_place(const int* __restrict__ src, const int* __restrict__ dst,
                        const float4* __restrict__ w, const float* __restrict__ outn,
                        const int* __restrict__ rowptr, int* __restrict__ cursor,
                        int* __restrict__ src_p, float* __restrict__ coef_p, int E) {
  int e = blockIdx.x * 256 + threadIdx.x;
  if (e >= E) return;
  int d = dst[e];
  int p = rowptr[d] + atomicAdd(&cursor[d], 1);
  int s = src[e];
  float4 v = w[e];
  src_p[p] = s;
  coef_p[p] = (v.x + v.y + v.z + v.w) * 0.25f * outn[s];
}

// ---------- gather: agg[n] = sum_{j in row n} coef_p[j] * h[src_p[j]]  (32 lanes/node, float4) ----------
__global__ __launch_bounds__(256) void k_gather(
    const float* __restrict__ h, const int* __restrict__ rowptr,
    const int* __restrict__ src_p, const float* __restrict__ coef_p,
    float* __restrict__ agg, int N) {
  int idx = blockIdx.x * 256 + threadIdx.x;
  int n = idx >> 5, c = idx & 31;
  if (n >= N) return;
  int beg = rowptr[n], end = rowptr[n + 1];
  float ax = 0.f, ay = 0.f, az = 0.f, aw = 0.f;
  for (int j = beg; j < end; ++j) {
    int s = src_p[j];
    float cf = coef_p[j];
    float4 v = ((const float4*)(h + (size_t)s * D))[c];
    ax = fmaf(v.x, cf, ax);
    ay = fmaf(v.y, cf, ay);
    az = fmaf(v.z, cf, az);
    aw = fmaf(v.w, cf, aw);
  }
  float4 r; r.x = ax; r.y = ay; r.z = az; r.w = aw;
  ((float4*)(agg + (size_t)n * D))[c] = r;
}

// ---------- GEMM: out[r] = (agg[r] * innm[r]) @ W  ; in-place-safe (out may == agg) ----------
// 4 waves/block; wave handles 16 rows x 128 cols; lane owns cols (2l, 2l+1).
// A operand is wave-uniform -> scalar s_loads (SMEM pipe); W from LDS (1 ds_read_b64/k).
__global__ __launch_bounds__(256) void k_gemm(
    const float* __restrict__ agg, const float* __restrict__ innorm,
    const float* __restrict__ W, float* __restrict__ out, int N) {
  __shared__ float Wl[D * D];  // 64 KiB
  for (int i = threadIdx.x; i < D * D / 4; i += 256)
    ((float4*)Wl)[i] = ((const float4*)W)[i];
  __syncthreads();
  const int lane = threadIdx.x & 63;
  const int wv = __builtin_amdgcn_readfirstlane(threadIdx.x >> 6);
  const int c0 = lane << 1;
  const int row0 = blockIdx.x * BM + wv * 16;
  if (row0 >= N) return;  // wave-uniform exit (no later syncthreads)

  float acc[16][2];
#pragma unroll
  for (int m = 0; m < 16; ++m) { acc[m][0] = 0.f; acc[m][1] = 0.f; }

  for (int k4 = 0; k4 < D; k4 += 4) {
    float4 a[16];
#pragma unroll
    for (int m = 0; m < 16; ++m) {
      int r = row0 + m;
      if (r > N - 1) r = N - 1;  // uniform clamp (only when N%16 != 0)
      a[m] = *(const float4*)(agg + (size_t)r * D + k4);  // uniform -> s_load
    }
#pragma unroll
    for (int kk = 0; kk < 4; ++kk) {
      float2 w2 = *(const float2*)(Wl + (k4 + kk) * D + c0);  // ds_read_b64, conflict-free
#pragma unroll
      for (int m = 0; m < 16; ++m) {
        float av = (kk == 0) ? a[m].x : (kk == 1) ? a[m].y : (kk == 2) ? a[m].z : a[m].w;
        acc[m][0] = fmaf(av, w2.x, acc[m][0]);
        acc[m][1] = fmaf(av, w2.y, acc[m][1]);
      }
    }
  }
#pragma unroll
  for (int m = 0; m < 16; ++m) {
    int r = row0 + m;
    if (r < N) {
      float sc = innorm[r];
      float2 o;
      o.x = acc[m][0] * sc;
      o.y = acc[m][1] * sc;
      *(float2*)(out + (size_t)r * D + c0) = o;
    }
  }
}

// ---------- fused relu + layernorm, one wave per row ----------
__global__ __launch_bounds__(256) void k_relu_ln(
    const float* __restrict__ in, const float* __restrict__ g, const float* __restrict__ b,
    float* __restrict__ out, int N) {
  int lane = threadIdx.x & 63, wv = threadIdx.x >> 6;
  int c0 = lane << 1;
  float2 g2 = *(const float2*)(g + c0);
  float2 b2 = *(const float2*)(b + c0);
  int nw = gridDim.x * 4;
  for (int r = blockIdx.x * 4 + wv; r < N; r += nw) {
    float2 v = *(const float2*)(in + (size_t)r * D + c0);
    float v0 = fmaxf(v.x, 0.f), v1 = fmaxf(v.y, 0.f);
    float s = v0 + v1;
#pragma unroll
    for (int off = 32; off; off >>= 1) s += __shfl_xor(s, off);
    float mu = s * (1.0f / D);
    float d0 = v0 - mu, d1 = v1 - mu;
    float vs = d0 * d0 + d1 * d1;
#pragma unroll
    for (int off = 32; off; off >>= 1) vs += __shfl_xor(vs, off);
    float rs = rsqrtf(vs * (1.0f / D) + EPS);
    float2 o;
    o.x = d0 * rs * g2.x + b2.x;
    o.y = d1 * rs * g2.y + b2.y;
    *(float2*)(out + (size_t)r * D + c0) = o;
  }
}

// ---------- readout: one block per graph, binary search sorted graph_ids ----------
__global__ void k_readout(const float* __restrict__ h, const int* __restrict__ gid,
                          float* __restrict__ out, int N) {
  int b = blockIdx.x;
  int t = threadIdx.x;  // 128 threads
  int lo = 0, hi = N;
  while (lo < hi) { int m = (lo + hi) >> 1; if (gid[m] < b) lo = m + 1; else hi = m; }
  int start = lo;
  int lo2 = start, hi2 = N;
  while (lo2 < hi2) { int m = (lo2 + hi2) >> 1; if (gid[m] < b + 1) lo2 = m + 1; else hi2 = m; }
  int end = lo2;
  float acc = 0.f;
  for (int n = start; n < end; ++n) acc += h[(size_t)n * D + t];
  out[b * D + t] = acc;
}

extern "C" void kernel_launch(void* const* d_in, const int* in_sizes, int n_in,
                              void* d_out, int out_size, void* d_ws, size_t ws_size,
                              hipStream_t stream) {
  const float* x    = (const float*)d_in[0];
  const float* w    = (const float*)d_in[1];
  const float* W1   = (const float*)d_in[2];
  const float* W2   = (const float*)d_in[3];
  const float* W3   = (const float*)d_in[4];
  const float* ln1g = (const float*)d_in[5];
  const float* ln1b = (const float*)d_in[6];
  const float* ln2g = (const float*)d_in[7];
  const float* ln2b = (const float*)d_in[8];
  const int* src = (const int*)d_in[9];
  const int* dst = (const int*)d_in[10];
  const int* gid = (const int*)d_in[11];
  const int N = in_sizes[0] / D;
  const int E = in_sizes[9];
  const int B = out_size / D;
  float* outp = (float*)d_out;

  // workspace layout
  float* A     = (float*)d_ws;               // [N*D] agg / gemm in-place
  float* Bb    = A + (size_t)N * D;          // [N*D] h
  float* outn  = Bb + (size_t)N * D;         // [N]
  float* innm  = outn + N;                   // [N]
  int*   ocnt  = (int*)(innm + N);           // [N]
  int*   icnt  = ocnt + N;                   // [N]
  int*   cursor= icnt + N;                   // [N]
  int*   rowptr= cursor + N;                 // [N+1]
  int*   src_p = rowptr + N + 1;             // [E]
  float* coef_p= (float*)(src_p + E);        // [E]

  const int eb = (E + 255) / 256;
  const int nb = (N + 255) / 256;
  const int gb = (int)(((size_t)N * 32 + 255) / 256);
  const int mb = (N + BM - 1) / BM;

  // ---- CSR build (once per call) ----
  hipMemsetAsync(ocnt, 0, sizeof(int) * 3 * (size_t)N, stream);  // ocnt, icnt, cursor
  k_count<<<eb, 256, 0, stream>>>(src, dst, ocnt, icnt, E);
  k_norm<<<nb, 256, 0, stream>>>(ocnt, icnt, outn, innm, N);
  k_scan<<<1, 1024, 0, stream>>>(icnt, rowptr, N);
  k_place<<<eb, 256, 0, stream>>>(src, dst, (const float4*)w, outn, rowptr, cursor,
                                  src_p, coef_p, E);

  // ---- layer 1: x -> A -> A -> Bb ----
  k_gather<<<gb, 256, 0, stream>>>(x, rowptr, src_p, coef_p, A, N);
  k_gemm<<<mb, 256, 0, stream>>>(A, innm, W1, A, N);
  k_relu_ln<<<2048, 256, 0, stream>>>(A, ln1g, ln1b, Bb, N);

  // ---- layer 2: Bb -> A -> A -> Bb ----
  k_gather<<<gb, 256, 0, stream>>>(Bb, rowptr, src_p, coef_p, A, N);
  k_gemm<<<mb, 256, 0, stream>>>(A, innm, W2, A, N);
  k_relu_ln<<<2048, 256, 0, stream>>>(A, ln2g, ln2b, Bb, N);

  // ---- layer 3: Bb -> A -> A ----
  k_gather<<<gb, 256, 0, stream>>>(Bb, rowptr, src_p, coef_p, A, N);
  k_gemm<<<mb, 256, 0, stream>>>(A, innm, W3, A, N);

  // ---- readout ----
  k_readout<<<B, D, 0, stream>>>(A, gid, outp, N);
}

// Round 4
// 606.741 us; speedup vs baseline: 8.0791x; 1.1684x over previous
//
#include <hip/hip_runtime.h>

#define D 128
#define BM 64  // rows per k_gemm block (4 waves x 16 rows)
constexpr float EPS = 1e-5f;

// ---------- int degree counts (out by src, in by dst) ----------
__global__ void k_count(const int* __restrict__ src, const int* __restrict__ dst,
                        int* __restrict__ ocnt, int* __restrict__ icnt, int E) {
  int e = blockIdx.x * 256 + threadIdx.x;
  if (e < E) {
    atomicAdd(&ocnt[src[e]], 1);
    atomicAdd(&icnt[dst[e]], 1);
  }
}

// ---------- norms from int degrees ----------
__global__ void k_norm(const int* __restrict__ ocnt, const int* __restrict__ icnt,
                       float* __restrict__ outn, float* __restrict__ innm, int N) {
  int n = blockIdx.x * 256 + threadIdx.x;
  if (n < N) {
    outn[n] = rsqrtf(fmaxf((float)ocnt[n], 1.0f));
    innm[n] = rsqrtf(fmaxf((float)icnt[n], 1.0f));
  }
}

// ---------- single-block exclusive scan of icnt -> rowptr[N+1] ----------
__global__ __launch_bounds__(1024) void k_scan(const int* __restrict__ cnt,
                                               int* __restrict__ rowptr, int N) {
  __shared__ int part[1024];
  int t = threadIdx.x;
  int chunk = (N + 1023) / 1024;
  int beg = t * chunk, end = min(beg + chunk, N);
  int s = 0;
  for (int i = beg; i < end; ++i) s += cnt[i];
  part[t] = s;
  __syncthreads();
  for (int off = 1; off < 1024; off <<= 1) {
    int v = (t >= off) ? part[t - off] : 0;
    __syncthreads();
    part[t] += v;
    __syncthreads();
  }
  int excl = (t == 0) ? 0 : part[t - 1];
  for (int i = beg; i < end; ++i) { rowptr[i] = excl; excl += cnt[i]; }
  if (t == 0) rowptr[N] = part[1023];
}

// ---------- place edges into CSR order; precompute coef = mean(w)*out_norm[src] ----------
__global__ void k_place(const int* __restrict__ src, const int* __restrict__ dst,
                        const float4* __restrict__ w, const float* __restrict__ outn,
                        const int* __restrict__ rowptr, int* __restrict__ cursor,
                        int* __restrict__ src_p, float* __restrict__ coef_p, int E) {
  int e = blockIdx.x * 256 + threadIdx.x;
  if (e >= E) return;
  int d = dst[e];
  int p = rowptr[d] + atomicAdd(&cursor[d], 1);
  int s = src[e];
  float4 v = w[e];
  src_p[p] = s;
  coef_p[p] = (v.x + v.y + v.z + v.w) * 0.25f * outn[s];
}

// ---------- gather: agg[n] = innm[n] * sum_{j in row n} coef_p[j] * h[src_p[j]] ----------
// 32 lanes/node (float4 per lane), 4x unrolled for memory-level parallelism.
__global__ __launch_bounds__(256) void k_gather(
    const float* __restrict__ h, const int* __restrict__ rowptr,
    const int* __restrict__ src_p, const float* __restrict__ coef_p,
    const float* __restrict__ innm, float* __restrict__ agg, int N) {
  int idx = blockIdx.x * 256 + threadIdx.x;
  int n = idx >> 5, c = idx & 31;
  if (n >= N) return;
  int beg = rowptr[n], end = rowptr[n + 1];
  float ax = 0.f, ay = 0.f, az = 0.f, aw = 0.f;
  int j = beg;
  for (; j + 4 <= end; j += 4) {
    int s0 = src_p[j + 0], s1 = src_p[j + 1], s2 = src_p[j + 2], s3 = src_p[j + 3];
    float f0 = coef_p[j + 0], f1 = coef_p[j + 1], f2 = coef_p[j + 2], f3 = coef_p[j + 3];
    float4 v0 = ((const float4*)(h + (size_t)s0 * D))[c];
    float4 v1 = ((const float4*)(h + (size_t)s1 * D))[c];
    float4 v2 = ((const float4*)(h + (size_t)s2 * D))[c];
    float4 v3 = ((const float4*)(h + (size_t)s3 * D))[c];
    ax = fmaf(v0.x, f0, ax); ay = fmaf(v0.y, f0, ay); az = fmaf(v0.z, f0, az); aw = fmaf(v0.w, f0, aw);
    ax = fmaf(v1.x, f1, ax); ay = fmaf(v1.y, f1, ay); az = fmaf(v1.z, f1, az); aw = fmaf(v1.w, f1, aw);
    ax = fmaf(v2.x, f2, ax); ay = fmaf(v2.y, f2, ay); az = fmaf(v2.z, f2, az); aw = fmaf(v2.w, f2, aw);
    ax = fmaf(v3.x, f3, ax); ay = fmaf(v3.y, f3, ay); az = fmaf(v3.z, f3, az); aw = fmaf(v3.w, f3, aw);
  }
  for (; j < end; ++j) {
    int s = src_p[j];
    float cf = coef_p[j];
    float4 v = ((const float4*)(h + (size_t)s * D))[c];
    ax = fmaf(v.x, cf, ax); ay = fmaf(v.y, cf, ay); az = fmaf(v.z, cf, az); aw = fmaf(v.w, cf, aw);
  }
  float sc = innm[n];  // fold in_norm here: gemm becomes pure A@W
  float4 r; r.x = ax * sc; r.y = ay * sc; r.z = az * sc; r.w = aw * sc;
  ((float4*)(agg + (size_t)n * D))[c] = r;
}

// ---------- fused GEMM + optional ReLU+LN: out[r] = ln(relu(agg[r] @ W)) ----------
// No LDS, no barrier. 4 waves/block; wave owns 16 rows x 128 cols; lane owns cols (2l,2l+1).
// A operand wave-uniform -> s_load (SMEM); W lane-varying -> global loads (L1-resident 64 KiB).
__global__ __launch_bounds__(256) void k_gemm_ln(
    const float* __restrict__ agg, const float* __restrict__ Wm,
    const float* __restrict__ g, const float* __restrict__ bta,
    float* __restrict__ out, int N, int do_ln) {
  const int lane = threadIdx.x & 63;
  const int wv = __builtin_amdgcn_readfirstlane(threadIdx.x >> 6);
  const int c0 = lane << 1;
  const int row0 = blockIdx.x * BM + wv * 16;
  if (row0 >= N) return;  // wave-uniform exit; no barriers anywhere

  float2 g2, b2;
  if (do_ln) { g2 = *(const float2*)(g + c0); b2 = *(const float2*)(bta + c0); }

  float acc[16][2];
#pragma unroll
  for (int m = 0; m < 16; ++m) { acc[m][0] = 0.f; acc[m][1] = 0.f; }

  for (int k4 = 0; k4 < D; k4 += 4) {
    // W rows k4..k4+3, this lane's 2 columns (L1-served, 8 B each)
    float2 w0 = *(const float2*)(Wm + (k4 + 0) * D + c0);
    float2 w1 = *(const float2*)(Wm + (k4 + 1) * D + c0);
    float2 w2 = *(const float2*)(Wm + (k4 + 2) * D + c0);
    float2 w3 = *(const float2*)(Wm + (k4 + 3) * D + c0);
    float4 a[16];
#pragma unroll
    for (int m = 0; m < 16; ++m) {
      int rm = row0 + m;
      if (rm > N - 1) rm = N - 1;  // uniform clamp, in-bounds read
      a[m] = *(const float4*)(agg + (size_t)rm * D + k4);  // uniform -> s_load_dwordx4
    }
#pragma unroll
    for (int m = 0; m < 16; ++m) {
      acc[m][0] = fmaf(a[m].x, w0.x, acc[m][0]); acc[m][1] = fmaf(a[m].x, w0.y, acc[m][1]);
      acc[m][0] = fmaf(a[m].y, w1.x, acc[m][0]); acc[m][1] = fmaf(a[m].y, w1.y, acc[m][1]);
      acc[m][0] = fmaf(a[m].z, w2.x, acc[m][0]); acc[m][1] = fmaf(a[m].z, w2.y, acc[m][1]);
      acc[m][0] = fmaf(a[m].w, w3.x, acc[m][0]); acc[m][1] = fmaf(a[m].w, w3.y, acc[m][1]);
    }
  }

#pragma unroll
  for (int m = 0; m < 16; ++m) {
    int r = row0 + m;
    float v0 = acc[m][0], v1 = acc[m][1];
    if (do_ln) {
      v0 = fmaxf(v0, 0.f); v1 = fmaxf(v1, 0.f);
      float s = v0 + v1;
#pragma unroll
      for (int off = 32; off; off >>= 1) s += __shfl_xor(s, off);
      float mu = s * (1.0f / D);
      float d0 = v0 - mu, d1 = v1 - mu;
      float vs = d0 * d0 + d1 * d1;
#pragma unroll
      for (int off = 32; off; off >>= 1) vs += __shfl_xor(vs, off);
      float rs = rsqrtf(vs * (1.0f / D) + EPS);
      v0 = d0 * rs * g2.x + b2.x;
      v1 = d1 * rs * g2.y + b2.y;
    }
    if (r < N) {
      float2 o; o.x = v0; o.y = v1;
      *(float2*)(out + (size_t)r * D + c0) = o;
    }
  }
}

// ---------- readout: one block per graph, binary search sorted graph_ids ----------
__global__ void k_readout(const float* __restrict__ h, const int* __restrict__ gid,
                          float* __restrict__ out, int N) {
  int b = blockIdx.x;
  int t = threadIdx.x;  // 128 threads
  int lo = 0, hi = N;
  while (lo < hi) { int m = (lo + hi) >> 1; if (gid[m] < b) lo = m + 1; else hi = m; }
  int start = lo;
  int lo2 = start, hi2 = N;
  while (lo2 < hi2) { int m = (lo2 + hi2) >> 1; if (gid[m] < b + 1) lo2 = m + 1; else hi2 = m; }
  int end = lo2;
  float acc = 0.f;
  for (int n = start; n < end; ++n) acc += h[(size_t)n * D + t];
  out[b * D + t] = acc;
}

extern "C" void kernel_launch(void* const* d_in, const int* in_sizes, int n_in,
                              void* d_out, int out_size, void* d_ws, size_t ws_size,
                              hipStream_t stream) {
  const float* x    = (const float*)d_in[0];
  const float* w    = (const float*)d_in[1];
  const float* W1   = (const float*)d_in[2];
  const float* W2   = (const float*)d_in[3];
  const float* W3   = (const float*)d_in[4];
  const float* ln1g = (const float*)d_in[5];
  const float* ln1b = (const float*)d_in[6];
  const float* ln2g = (const float*)d_in[7];
  const float* ln2b = (const float*)d_in[8];
  const int* src = (const int*)d_in[9];
  const int* dst = (const int*)d_in[10];
  const int* gid = (const int*)d_in[11];
  const int N = in_sizes[0] / D;
  const int E = in_sizes[9];
  const int B = out_size / D;
  float* outp = (float*)d_out;

  // workspace layout
  float* A     = (float*)d_ws;               // [N*D] agg (already scaled by in_norm)
  float* Bb    = A + (size_t)N * D;          // [N*D] h
  float* outn  = Bb + (size_t)N * D;         // [N]
  float* innm  = outn + N;                   // [N]
  int*   ocnt  = (int*)(innm + N);           // [N]
  int*   icnt  = ocnt + N;                   // [N]
  int*   cursor= icnt + N;                   // [N]
  int*   rowptr= cursor + N;                 // [N+1]
  int*   src_p = rowptr + N + 1;             // [E]
  float* coef_p= (float*)(src_p + E);        // [E]

  const int eb = (E + 255) / 256;
  const int nb = (N + 255) / 256;
  const int gb = (int)(((size_t)N * 32 + 255) / 256);
  const int mb = (N + BM - 1) / BM;

  // ---- CSR build (once per call) ----
  hipMemsetAsync(ocnt, 0, sizeof(int) * 3 * (size_t)N, stream);  // ocnt, icnt, cursor
  k_count<<<eb, 256, 0, stream>>>(src, dst, ocnt, icnt, E);
  k_norm<<<nb, 256, 0, stream>>>(ocnt, icnt, outn, innm, N);
  k_scan<<<1, 1024, 0, stream>>>(icnt, rowptr, N);
  k_place<<<eb, 256, 0, stream>>>(src, dst, (const float4*)w, outn, rowptr, cursor,
                                  src_p, coef_p, E);

  // ---- layer 1: x -> A -> Bb ----
  k_gather<<<gb, 256, 0, stream>>>(x, rowptr, src_p, coef_p, innm, A, N);
  k_gemm_ln<<<mb, 256, 0, stream>>>(A, W1, ln1g, ln1b, Bb, N, 1);

  // ---- layer 2: Bb -> A -> Bb ----
  k_gather<<<gb, 256, 0, stream>>>(Bb, rowptr, src_p, coef_p, innm, A, N);
  k_gemm_ln<<<mb, 256, 0, stream>>>(A, W2, ln2g, ln2b, Bb, N, 1);

  // ---- layer 3: Bb -> A -> Bb (no relu/ln) ----
  k_gather<<<gb, 256, 0, stream>>>(Bb, rowptr, src_p, coef_p, innm, A, N);
  k_gemm_ln<<<mb, 256, 0, stream>>>(A, W3, nullptr, nullptr, Bb, N, 0);

  // ---- readout ----
  k_readout<<<B, D, 0, stream>>>(Bb, gid, outp, N);
}

// Round 5
// 540.654 us; speedup vs baseline: 9.0666x; 1.1222x over previous
//
#include <hip/hip_runtime.h>

#define D 128
#define BM 64  // rows per k_gemm block (4 waves x 16 rows)
constexpr float EPS = 1e-5f;

// ---------- int degree counts (out by src, in by dst) ----------
__global__ void k_count(const int* __restrict__ src, const int* __restrict__ dst,
                        int* __restrict__ ocnt, int* __restrict__ icnt, int E) {
  int e = blockIdx.x * 256 + threadIdx.x;
  if (e < E) {
    atomicAdd(&ocnt[src[e]], 1);
    atomicAdd(&icnt[dst[e]], 1);
  }
}

// ---------- norms from int degrees ----------
__global__ void k_norm(const int* __restrict__ ocnt, const int* __restrict__ icnt,
                       float* __restrict__ outn, float* __restrict__ innm, int N) {
  int n = blockIdx.x * 256 + threadIdx.x;
  if (n < N) {
    outn[n] = rsqrtf(fmaxf((float)ocnt[n], 1.0f));
    innm[n] = rsqrtf(fmaxf((float)icnt[n], 1.0f));
  }
}

// ---------- scan level 1: per-block (256-elem chunk) sums ----------
__global__ __launch_bounds__(256) void k_bsum(const int* __restrict__ cnt,
                                              int* __restrict__ bsum, int N) {
  int i = blockIdx.x * 256 + threadIdx.x;
  int v = (i < N) ? cnt[i] : 0;
#pragma unroll
  for (int off = 32; off; off >>= 1) v += __shfl_xor(v, off);
  __shared__ int ws[4];
  if ((threadIdx.x & 63) == 0) ws[threadIdx.x >> 6] = v;
  __syncthreads();
  if (threadIdx.x == 0) bsum[blockIdx.x] = ws[0] + ws[1] + ws[2] + ws[3];
}

// ---------- scan level 2: single-block exclusive scan (small n) ----------
__global__ __launch_bounds__(1024) void k_scan(const int* __restrict__ cnt,
                                               int* __restrict__ rowptr, int N) {
  __shared__ int part[1024];
  int t = threadIdx.x;
  int chunk = (N + 1023) / 1024;
  int beg = t * chunk, end = min(beg + chunk, N);
  int s = 0;
  for (int i = beg; i < end; ++i) s += cnt[i];
  part[t] = s;
  __syncthreads();
  for (int off = 1; off < 1024; off <<= 1) {
    int v = (t >= off) ? part[t - off] : 0;
    __syncthreads();
    part[t] += v;
    __syncthreads();
  }
  int excl = (t == 0) ? 0 : part[t - 1];
  for (int i = beg; i < end; ++i) { rowptr[i] = excl; excl += cnt[i]; }
  if (t == 0) rowptr[N] = part[1023];
}

// ---------- scan level 3: intra-block scan + block prefix -> rowptr ----------
__global__ __launch_bounds__(256) void k_scan3(const int* __restrict__ cnt,
                                               const int* __restrict__ bptr,
                                               int* __restrict__ rowptr, int N, int nbs) {
  int i = blockIdx.x * 256 + threadIdx.x;
  int lane = threadIdx.x & 63, wv = threadIdx.x >> 6;
  int orig = (i < N) ? cnt[i] : 0;
  int v = orig;
#pragma unroll
  for (int off = 1; off < 64; off <<= 1) {
    int t = __shfl_up(v, off);
    if (lane >= off) v += t;
  }
  __shared__ int wsum[4];
  if (lane == 63) wsum[wv] = v;
  __syncthreads();
  int woff = 0;
#pragma unroll
  for (int k = 0; k < 4; ++k)
    if (k < wv) woff += wsum[k];
  int excl = bptr[blockIdx.x] + woff + (v - orig);
  if (i < N) rowptr[i] = excl;
  if (blockIdx.x == 0 && threadIdx.x == 0) rowptr[N] = bptr[nbs];
}

// ---------- place edges into CSR order; precompute coef = mean(w)*out_norm[src] ----------
__global__ void k_place(const int* __restrict__ src, const int* __restrict__ dst,
                        const float4* __restrict__ w, const float* __restrict__ outn,
                        const int* __restrict__ rowptr, int* __restrict__ cursor,
                        int* __restrict__ src_p, float* __restrict__ coef_p, int E) {
  int e = blockIdx.x * 256 + threadIdx.x;
  if (e >= E) return;
  int d = dst[e];
  int p = rowptr[d] + atomicAdd(&cursor[d], 1);
  int s = src[e];
  float4 v = w[e];
  src_p[p] = s;
  coef_p[p] = (v.x + v.y + v.z + v.w) * 0.25f * outn[s];
}

// ---------- gather: agg[n] = innm[n] * sum_{j in row n} coef_p[j] * h[src_p[j]] ----------
// 32 lanes/node (float4 per lane), 4x unrolled for memory-level parallelism.
__global__ __launch_bounds__(256) void k_gather(
    const float* __restrict__ h, const int* __restrict__ rowptr,
    const int* __restrict__ src_p, const float* __restrict__ coef_p,
    const float* __restrict__ innm, float* __restrict__ agg, int N) {
  int idx = blockIdx.x * 256 + threadIdx.x;
  int n = idx >> 5, c = idx & 31;
  if (n >= N) return;
  int beg = rowptr[n], end = rowptr[n + 1];
  float ax = 0.f, ay = 0.f, az = 0.f, aw = 0.f;
  int j = beg;
  for (; j + 4 <= end; j += 4) {
    int s0 = src_p[j + 0], s1 = src_p[j + 1], s2 = src_p[j + 2], s3 = src_p[j + 3];
    float f0 = coef_p[j + 0], f1 = coef_p[j + 1], f2 = coef_p[j + 2], f3 = coef_p[j + 3];
    float4 v0 = ((const float4*)(h + (size_t)s0 * D))[c];
    float4 v1 = ((const float4*)(h + (size_t)s1 * D))[c];
    float4 v2 = ((const float4*)(h + (size_t)s2 * D))[c];
    float4 v3 = ((const float4*)(h + (size_t)s3 * D))[c];
    ax = fmaf(v0.x, f0, ax); ay = fmaf(v0.y, f0, ay); az = fmaf(v0.z, f0, az); aw = fmaf(v0.w, f0, aw);
    ax = fmaf(v1.x, f1, ax); ay = fmaf(v1.y, f1, ay); az = fmaf(v1.z, f1, az); aw = fmaf(v1.w, f1, aw);
    ax = fmaf(v2.x, f2, ax); ay = fmaf(v2.y, f2, ay); az = fmaf(v2.z, f2, az); aw = fmaf(v2.w, f2, aw);
    ax = fmaf(v3.x, f3, ax); ay = fmaf(v3.y, f3, ay); az = fmaf(v3.z, f3, az); aw = fmaf(v3.w, f3, aw);
  }
  for (; j < end; ++j) {
    int s = src_p[j];
    float cf = coef_p[j];
    float4 v = ((const float4*)(h + (size_t)s * D))[c];
    ax = fmaf(v.x, cf, ax); ay = fmaf(v.y, cf, ay); az = fmaf(v.z, cf, az); aw = fmaf(v.w, cf, aw);
  }
  float sc = innm[n];  // fold in_norm here: gemm becomes pure A@W
  float4 r; r.x = ax * sc; r.y = ay * sc; r.z = az * sc; r.w = aw * sc;
  ((float4*)(agg + (size_t)n * D))[c] = r;
}

// ---------- fused GEMM + optional ReLU+LN: out[r] = ln(relu(agg[r] @ W)) ----------
// No LDS, no barrier. 4 waves/block; wave owns 16 rows x 128 cols; lane owns cols (2l,2l+1).
// A operand wave-uniform -> s_load (SMEM); W lane-varying -> global loads (L1-resident 64 KiB).
__global__ __launch_bounds__(256) void k_gemm_ln(
    const float* __restrict__ agg, const float* __restrict__ Wm,
    const float* __restrict__ g, const float* __restrict__ bta,
    float* __restrict__ out, int N, int do_ln) {
  const int lane = threadIdx.x & 63;
  const int wv = __builtin_amdgcn_readfirstlane(threadIdx.x >> 6);
  const int c0 = lane << 1;
  const int row0 = blockIdx.x * BM + wv * 16;
  if (row0 >= N) return;  // wave-uniform exit; no barriers anywhere

  float2 g2, b2;
  if (do_ln) { g2 = *(const float2*)(g + c0); b2 = *(const float2*)(bta + c0); }

  float acc[16][2];
#pragma unroll
  for (int m = 0; m < 16; ++m) { acc[m][0] = 0.f; acc[m][1] = 0.f; }

  for (int k4 = 0; k4 < D; k4 += 4) {
    // W rows k4..k4+3, this lane's 2 columns (L1-served, 8 B each)
    float2 w0 = *(const float2*)(Wm + (k4 + 0) * D + c0);
    float2 w1 = *(const float2*)(Wm + (k4 + 1) * D + c0);
    float2 w2 = *(const float2*)(Wm + (k4 + 2) * D + c0);
    float2 w3 = *(const float2*)(Wm + (k4 + 3) * D + c0);
    float4 a[16];
#pragma unroll
    for (int m = 0; m < 16; ++m) {
      int rm = row0 + m;
      if (rm > N - 1) rm = N - 1;  // uniform clamp, in-bounds read
      a[m] = *(const float4*)(agg + (size_t)rm * D + k4);  // uniform -> s_load_dwordx4
    }
#pragma unroll
    for (int m = 0; m < 16; ++m) {
      acc[m][0] = fmaf(a[m].x, w0.x, acc[m][0]); acc[m][1] = fmaf(a[m].x, w0.y, acc[m][1]);
      acc[m][0] = fmaf(a[m].y, w1.x, acc[m][0]); acc[m][1] = fmaf(a[m].y, w1.y, acc[m][1]);
      acc[m][0] = fmaf(a[m].z, w2.x, acc[m][0]); acc[m][1] = fmaf(a[m].z, w2.y, acc[m][1]);
      acc[m][0] = fmaf(a[m].w, w3.x, acc[m][0]); acc[m][1] = fmaf(a[m].w, w3.y, acc[m][1]);
    }
  }

#pragma unroll
  for (int m = 0; m < 16; ++m) {
    int r = row0 + m;
    float v0 = acc[m][0], v1 = acc[m][1];
    if (do_ln) {
      v0 = fmaxf(v0, 0.f); v1 = fmaxf(v1, 0.f);
      float s = v0 + v1;
#pragma unroll
      for (int off = 32; off; off >>= 1) s += __shfl_xor(s, off);
      float mu = s * (1.0f / D);
      float d0 = v0 - mu, d1 = v1 - mu;
      float vs = d0 * d0 + d1 * d1;
#pragma unroll
      for (int off = 32; off; off >>= 1) vs += __shfl_xor(vs, off);
      float rs = rsqrtf(vs * (1.0f / D) + EPS);
      v0 = d0 * rs * g2.x + b2.x;
      v1 = d1 * rs * g2.y + b2.y;
    }
    if (r < N) {
      float2 o; o.x = v0; o.y = v1;
      *(float2*)(out + (size_t)r * D + c0) = o;
    }
  }
}

// ---------- readout: one block per graph, binary search sorted graph_ids ----------
__global__ void k_readout(const float* __restrict__ h, const int* __restrict__ gid,
                          float* __restrict__ out, int N) {
  int b = blockIdx.x;
  int t = threadIdx.x;  // 128 threads
  int lo = 0, hi = N;
  while (lo < hi) { int m = (lo + hi) >> 1; if (gid[m] < b) lo = m + 1; else hi = m; }
  int start = lo;
  int lo2 = start, hi2 = N;
  while (lo2 < hi2) { int m = (lo2 + hi2) >> 1; if (gid[m] < b + 1) lo2 = m + 1; else hi2 = m; }
  int end = lo2;
  float acc = 0.f;
  for (int n = start; n < end; ++n) acc += h[(size_t)n * D + t];
  out[b * D + t] = acc;
}

extern "C" void kernel_launch(void* const* d_in, const int* in_sizes, int n_in,
                              void* d_out, int out_size, void* d_ws, size_t ws_size,
                              hipStream_t stream) {
  const float* x    = (const float*)d_in[0];
  const float* w    = (const float*)d_in[1];
  const float* W1   = (const float*)d_in[2];
  const float* W2   = (const float*)d_in[3];
  const float* W3   = (const float*)d_in[4];
  const float* ln1g = (const float*)d_in[5];
  const float* ln1b = (const float*)d_in[6];
  const float* ln2g = (const float*)d_in[7];
  const float* ln2b = (const float*)d_in[8];
  const int* src = (const int*)d_in[9];
  const int* dst = (const int*)d_in[10];
  const int* gid = (const int*)d_in[11];
  const int N = in_sizes[0] / D;
  const int E = in_sizes[9];
  const int B = out_size / D;
  float* outp = (float*)d_out;

  // workspace layout
  float* A     = (float*)d_ws;               // [N*D] agg (already scaled by in_norm)
  float* Bb    = A + (size_t)N * D;          // [N*D] h
  float* outn  = Bb + (size_t)N * D;         // [N]
  float* innm  = outn + N;                   // [N]
  int*   ocnt  = (int*)(innm + N);           // [N]
  int*   icnt  = ocnt + N;                   // [N]
  int*   cursor= icnt + N;                   // [N]
  int*   rowptr= cursor + N;                 // [N+1]
  int*   src_p = rowptr + N + 1;             // [E]
  float* coef_p= (float*)(src_p + E);        // [E]
  int*   bsum  = (int*)(coef_p + E);         // [nbs]
  int*   bptr  = bsum + ((N + 255) / 256);   // [nbs+1]

  const int eb = (E + 255) / 256;
  const int nb = (N + 255) / 256;
  const int nbs = (N + 255) / 256;
  const int gb = (int)(((size_t)N * 32 + 255) / 256);
  const int mb = (N + BM - 1) / BM;

  // ---- CSR build (once per call) ----
  hipMemsetAsync(ocnt, 0, sizeof(int) * 3 * (size_t)N, stream);  // ocnt, icnt, cursor
  k_count<<<eb, 256, 0, stream>>>(src, dst, ocnt, icnt, E);
  k_norm<<<nb, 256, 0, stream>>>(ocnt, icnt, outn, innm, N);
  // device-wide exclusive scan of icnt -> rowptr (3 levels)
  k_bsum<<<nbs, 256, 0, stream>>>(icnt, bsum, N);
  k_scan<<<1, 1024, 0, stream>>>(bsum, bptr, nbs);
  k_scan3<<<nbs, 256, 0, stream>>>(icnt, bptr, rowptr, N, nbs);
  k_place<<<eb, 256, 0, stream>>>(src, dst, (const float4*)w, outn, rowptr, cursor,
                                  src_p, coef_p, E);

  // ---- layer 1: x -> A -> Bb ----
  k_gather<<<gb, 256, 0, stream>>>(x, rowptr, src_p, coef_p, innm, A, N);
  k_gemm_ln<<<mb, 256, 0, stream>>>(A, W1, ln1g, ln1b, Bb, N, 1);

  // ---- layer 2: Bb -> A -> Bb ----
  k_gather<<<gb, 256, 0, stream>>>(Bb, rowptr, src_p, coef_p, innm, A, N);
  k_gemm_ln<<<mb, 256, 0, stream>>>(A, W2, ln2g, ln2b, Bb, N, 1);

  // ---- layer 3: Bb -> A -> Bb (no relu/ln) ----
  k_gather<<<gb, 256, 0, stream>>>(Bb, rowptr, src_p, coef_p, innm, A, N);
  k_gemm_ln<<<mb, 256, 0, stream>>>(A, W3, nullptr, nullptr, Bb, N, 0);

  // ---- readout ----
  k_readout<<<B, D, 0, stream>>>(Bb, gid, outp, N);
}

// Round 7
// 346.064 us; speedup vs baseline: 14.1647x; 1.5623x over previous
//
#include <hip/hip_runtime.h>

#define D 128
constexpr float EPS = 1e-5f;

typedef short bf16x8 __attribute__((ext_vector_type(8)));
typedef float f32x4 __attribute__((ext_vector_type(4)));

__device__ __forceinline__ uint f2bf(float f) {  // RNE f32->bf16 (finite inputs)
  union { float f; uint u; } v; v.f = f;
  return (v.u + 0x7fffu + ((v.u >> 16) & 1u)) >> 16;
}
__device__ __forceinline__ float bflo(uint u) {  // low bf16 of packed u32
  union { uint u; float f; } v; v.u = u << 16; return v.f;
}
__device__ __forceinline__ float bfhi(uint u) {  // high bf16
  union { uint u; float f; } v; v.u = u & 0xffff0000u; return v.f;
}

// ---------- int degree counts ----------
__global__ void k_count(const int* __restrict__ src, const int* __restrict__ dst,
                        int* __restrict__ ocnt, int* __restrict__ icnt, int E) {
  int e = blockIdx.x * 256 + threadIdx.x;
  if (e < E) {
    atomicAdd(&ocnt[src[e]], 1);
    atomicAdd(&icnt[dst[e]], 1);
  }
}

// ---------- norms from int degrees ----------
__global__ void k_norm(const int* __restrict__ ocnt, const int* __restrict__ icnt,
                       float* __restrict__ outn, float* __restrict__ innm, int N) {
  int n = blockIdx.x * 256 + threadIdx.x;
  if (n < N) {
    outn[n] = rsqrtf(fmaxf((float)ocnt[n], 1.0f));
    innm[n] = rsqrtf(fmaxf((float)icnt[n], 1.0f));
  }
}

// ---------- scan level 1: per-block sums ----------
__global__ __launch_bounds__(256) void k_bsum(const int* __restrict__ cnt,
                                              int* __restrict__ bsum, int N) {
  int i = blockIdx.x * 256 + threadIdx.x;
  int v = (i < N) ? cnt[i] : 0;
#pragma unroll
  for (int off = 32; off; off >>= 1) v += __shfl_xor(v, off);
  __shared__ int ws[4];
  if ((threadIdx.x & 63) == 0) ws[threadIdx.x >> 6] = v;
  __syncthreads();
  if (threadIdx.x == 0) bsum[blockIdx.x] = ws[0] + ws[1] + ws[2] + ws[3];
}

// ---------- scan level 2: single-block exclusive scan ----------
__global__ __launch_bounds__(1024) void k_scan(const int* __restrict__ cnt,
                                               int* __restrict__ rowptr, int N) {
  __shared__ int part[1024];
  int t = threadIdx.x;
  int chunk = (N + 1023) / 1024;
  int beg = t * chunk, end = min(beg + chunk, N);
  int s = 0;
  for (int i = beg; i < end; ++i) s += cnt[i];
  part[t] = s;
  __syncthreads();
  for (int off = 1; off < 1024; off <<= 1) {
    int v = (t >= off) ? part[t - off] : 0;
    __syncthreads();
    part[t] += v;
    __syncthreads();
  }
  int excl = (t == 0) ? 0 : part[t - 1];
  for (int i = beg; i < end; ++i) { rowptr[i] = excl; excl += cnt[i]; }
  if (t == 0) rowptr[N] = part[1023];
}

// ---------- scan level 3: intra-block scan + block prefix ----------
__global__ __launch_bounds__(256) void k_scan3(const int* __restrict__ cnt,
                                               const int* __restrict__ bptr,
                                               int* __restrict__ rowptr, int N, int nbs) {
  int i = blockIdx.x * 256 + threadIdx.x;
  int lane = threadIdx.x & 63, wv = threadIdx.x >> 6;
  int orig = (i < N) ? cnt[i] : 0;
  int v = orig;
#pragma unroll
  for (int off = 1; off < 64; off <<= 1) {
    int t = __shfl_up(v, off);
    if (lane >= off) v += t;
  }
  __shared__ int wsum[4];
  if (lane == 63) wsum[wv] = v;
  __syncthreads();
  int woff = 0;
#pragma unroll
  for (int k = 0; k < 4; ++k)
    if (k < wv) woff += wsum[k];
  int excl = bptr[blockIdx.x] + woff + (v - orig);
  if (i < N) rowptr[i] = excl;
  if (blockIdx.x == 0 && threadIdx.x == 0) rowptr[N] = bptr[nbs];
}

// ---------- place edges into CSR; coef = mean(w)*out_norm[src] ----------
__global__ void k_place(const int* __restrict__ src, const int* __restrict__ dst,
                        const float4* __restrict__ w, const float* __restrict__ outn,
                        const int* __restrict__ rowptr, int* __restrict__ cursor,
                        int* __restrict__ src_p, float* __restrict__ coef_p, int E) {
  int e = blockIdx.x * 256 + threadIdx.x;
  if (e >= E) return;
  int d = dst[e];
  int p = rowptr[d] + atomicAdd(&cursor[d], 1);
  int s = src[e];
  float4 v = w[e];
  src_p[p] = s;
  coef_p[p] = (v.x + v.y + v.z + v.w) * 0.25f * outn[s];
}

// ---------- f32 -> bf16 bulk convert (8 elems/thread) ----------
__global__ void k_cvt(const float4* __restrict__ in, uint4* __restrict__ outp, int n8) {
  int i = blockIdx.x * 256 + threadIdx.x;
  if (i < n8) {
    float4 p = in[i * 2], q = in[i * 2 + 1];
    uint4 o;
    o.x = f2bf(p.x) | (f2bf(p.y) << 16);
    o.y = f2bf(p.z) | (f2bf(p.w) << 16);
    o.z = f2bf(q.x) | (f2bf(q.y) << 16);
    o.w = f2bf(q.z) | (f2bf(q.w) << 16);
    outp[i] = o;
  }
}

// ---------- W f32[128][128] -> bf16 MFMA B-fragment layout ----------
// frag (ks,ct), lane l holds B[k][col]: k=ks*32+(l>>4)*8+j, col=ct*16+(l&15).
__global__ void k_cvt_wf(const float* __restrict__ Wsrc, ushort* __restrict__ Wf) {
  int tid = blockIdx.x * 256 + threadIdx.x;
  if (tid >= 2048) return;
  int lane = tid & 63;
  int frag = tid >> 6;            // 0..31
  int ks = frag >> 3, ct = frag & 7;
  int col = ct * 16 + (lane & 15);
  int kb = ks * 32 + (lane >> 4) * 8;
  uint p[8];
#pragma unroll
  for (int j = 0; j < 8; ++j) p[j] = f2bf(Wsrc[(kb + j) * D + col]);
  uint4 o;
  o.x = p[0] | (p[1] << 16);
  o.y = p[2] | (p[3] << 16);
  o.z = p[4] | (p[5] << 16);
  o.w = p[6] | (p[7] << 16);
  *(uint4*)(Wf + (size_t)tid * 8) = o;
}

// ---------- gather (bf16 h): agg[n] = bf16( innm[n] * sum coef*h[src] ) ----------
// 16 lanes/node, each lane owns 8 cols (16 B), fp32 accum, 4x unrolled.
__global__ __launch_bounds__(256) void k_gather_bf(
    const ushort* __restrict__ h, const int* __restrict__ rowptr,
    const int* __restrict__ src_p, const float* __restrict__ coef_p,
    const float* __restrict__ innm, ushort* __restrict__ agg, int N) {
  int idx = blockIdx.x * 256 + threadIdx.x;
  int n = idx >> 4, c = idx & 15;
  if (n >= N) return;
  int beg = rowptr[n], end = rowptr[n + 1];
  float a0 = 0, a1 = 0, a2 = 0, a3 = 0, a4 = 0, a5 = 0, a6 = 0, a7 = 0;
#define ACC8(q, f)                                        \
  a0 = fmaf(bflo(q.x), f, a0); a1 = fmaf(bfhi(q.x), f, a1); \
  a2 = fmaf(bflo(q.y), f, a2); a3 = fmaf(bfhi(q.y), f, a3); \
  a4 = fmaf(bflo(q.z), f, a4); a5 = fmaf(bfhi(q.z), f, a5); \
  a6 = fmaf(bflo(q.w), f, a6); a7 = fmaf(bfhi(q.w), f, a7);
  int j = beg;
  for (; j + 4 <= end; j += 4) {
    int s0 = src_p[j], s1 = src_p[j + 1], s2 = src_p[j + 2], s3 = src_p[j + 3];
    float f0 = coef_p[j], f1 = coef_p[j + 1], f2 = coef_p[j + 2], f3 = coef_p[j + 3];
    uint4 q0 = *(const uint4*)(h + (size_t)s0 * D + c * 8);
    uint4 q1 = *(const uint4*)(h + (size_t)s1 * D + c * 8);
    uint4 q2 = *(const uint4*)(h + (size_t)s2 * D + c * 8);
    uint4 q3 = *(const uint4*)(h + (size_t)s3 * D + c * 8);
    ACC8(q0, f0) ACC8(q1, f1) ACC8(q2, f2) ACC8(q3, f3)
  }
  for (; j < end; ++j) {
    int s = src_p[j];
    float f = coef_p[j];
    uint4 q = *(const uint4*)(h + (size_t)s * D + c * 8);
    ACC8(q, f)
  }
#undef ACC8
  float sc = innm[n];
  uint4 o;
  o.x = f2bf(a0 * sc) | (f2bf(a1 * sc) << 16);
  o.y = f2bf(a2 * sc) | (f2bf(a3 * sc) << 16);
  o.z = f2bf(a4 * sc) | (f2bf(a5 * sc) << 16);
  o.w = f2bf(a6 * sc) | (f2bf(a7 * sc) << 16);
  *(uint4*)(agg + (size_t)n * D + c * 8) = o;
}

// ---------- MFMA GEMM + fused ReLU+LN ----------
// 4 waves/block, wave owns 16 rows x 128 cols: 4 ksteps x 8 coltiles of
// mfma_f32_16x16x32_bf16. do_ln: bf16 out (via per-wave LDS transpose);
// else f32 out. LDS is wave-private slots of 16*D floats (f32 path needs
// the full 8 KiB/wave; bf16 path uses half). No block barriers.
__global__ __launch_bounds__(256) void k_gemm_mfma(
    const ushort* __restrict__ agg, const ushort* __restrict__ Wf,
    const float* __restrict__ g, const float* __restrict__ bta,
    void* __restrict__ out, int N, int do_ln) {
  __shared__ float lds[4][16 * D];  // 32 KiB total: 8 KiB per wave
  const int lane = threadIdx.x & 63;
  const int wv = threadIdx.x >> 6;
  const int row0 = blockIdx.x * 64 + wv * 16;
  if (row0 >= N) return;
  const int lc = lane & 15, lg = lane >> 4;

  int arow = row0 + lc;
  if (arow > N - 1) arow = N - 1;
  const ushort* aptr = agg + (size_t)arow * D + lg * 8;

  f32x4 acc[8];
#pragma unroll
  for (int ct = 0; ct < 8; ++ct) acc[ct] = (f32x4){0.f, 0.f, 0.f, 0.f};

#pragma unroll
  for (int ks = 0; ks < 4; ++ks) {
    bf16x8 a = *(const bf16x8*)(aptr + ks * 32);
    const ushort* wp = Wf + ((size_t)(ks * 8) * 64 + lane) * 8;
#pragma unroll
    for (int ct = 0; ct < 8; ++ct) {
      bf16x8 b = *(const bf16x8*)(wp + ct * 512);
      acc[ct] = __builtin_amdgcn_mfma_f32_16x16x32_bf16(a, b, acc[ct], 0, 0, 0);
    }
  }

  if (do_ln) {
    float v[8][4];
#pragma unroll
    for (int ct = 0; ct < 8; ++ct)
#pragma unroll
      for (int j = 0; j < 4; ++j) v[ct][j] = fmaxf(acc[ct][j], 0.f);
    float mu[4], rs[4];
#pragma unroll
    for (int j = 0; j < 4; ++j) {
      float s = 0.f;
#pragma unroll
      for (int ct = 0; ct < 8; ++ct) s += v[ct][j];
#pragma unroll
      for (int off = 1; off < 16; off <<= 1) s += __shfl_xor(s, off);
      mu[j] = s * (1.0f / D);
    }
#pragma unroll
    for (int j = 0; j < 4; ++j) {
      float q = 0.f;
#pragma unroll
      for (int ct = 0; ct < 8; ++ct) {
        v[ct][j] -= mu[j];
        q = fmaf(v[ct][j], v[ct][j], q);
      }
#pragma unroll
      for (int off = 1; off < 16; off <<= 1) q += __shfl_xor(q, off);
      rs[j] = rsqrtf(q * (1.0f / D) + EPS);
    }
    ushort* lp = (ushort*)&lds[wv][0];  // 16x128 bf16 (4 KiB of the 8 KiB slot)
#pragma unroll
    for (int ct = 0; ct < 8; ++ct) {
      float gc = g[ct * 16 + lc], bc = bta[ct * 16 + lc];
#pragma unroll
      for (int j = 0; j < 4; ++j)
        lp[(lg * 4 + j) * D + ct * 16 + lc] = (ushort)f2bf(fmaf(v[ct][j] * rs[j], gc, bc));
    }
    __builtin_amdgcn_wave_barrier();  // order LDS write->read (same wave)
    int r = row0 + (lane >> 2);  // lane copies 32 ushorts = quarter row
    if (r < N) {
      ushort* ob = (ushort*)out + (size_t)row0 * D + lane * 32;
#pragma unroll
      for (int i = 0; i < 4; ++i)
        ((uint4*)ob)[i] = ((const uint4*)(lp + lane * 32))[i];
    }
  } else {
    float* lp = &lds[wv][0];  // 16x128 f32 (full 8 KiB slot)
#pragma unroll
    for (int ct = 0; ct < 8; ++ct)
#pragma unroll
      for (int j = 0; j < 4; ++j)
        lp[(lg * 4 + j) * D + ct * 16 + lc] = acc[ct][j];
    __builtin_amdgcn_wave_barrier();  // order LDS write->read (same wave)
    int r = row0 + (lane >> 2);  // lane copies 32 floats = quarter row
    if (r < N) {
      float* ob = (float*)out + (size_t)row0 * D + lane * 32;
#pragma unroll
      for (int i = 0; i < 8; ++i)
        ((float4*)ob)[i] = ((const float4*)(lp + lane * 32))[i];
    }
  }
}

// ---------- readout: one block per graph (f32 h3) ----------
__global__ void k_readout(const float* __restrict__ h, const int* __restrict__ gid,
                          float* __restrict__ out, int N) {
  int b = blockIdx.x;
  int t = threadIdx.x;  // 128 threads
  int lo = 0, hi = N;
  while (lo < hi) { int m = (lo + hi) >> 1; if (gid[m] < b) lo = m + 1; else hi = m; }
  int start = lo;
  int lo2 = start, hi2 = N;
  while (lo2 < hi2) { int m = (lo2 + hi2) >> 1; if (gid[m] < b + 1) lo2 = m + 1; else hi2 = m; }
  int end = lo2;
  float acc = 0.f;
  for (int n = start; n < end; ++n) acc += h[(size_t)n * D + t];
  out[b * D + t] = acc;
}

extern "C" void kernel_launch(void* const* d_in, const int* in_sizes, int n_in,
                              void* d_out, int out_size, void* d_ws, size_t ws_size,
                              hipStream_t stream) {
  const float* x    = (const float*)d_in[0];
  const float* w    = (const float*)d_in[1];
  const float* W1   = (const float*)d_in[2];
  const float* W2   = (const float*)d_in[3];
  const float* W3   = (const float*)d_in[4];
  const float* ln1g = (const float*)d_in[5];
  const float* ln1b = (const float*)d_in[6];
  const float* ln2g = (const float*)d_in[7];
  const float* ln2b = (const float*)d_in[8];
  const int* src = (const int*)d_in[9];
  const int* dst = (const int*)d_in[10];
  const int* gid = (const int*)d_in[11];
  const int N = in_sizes[0] / D;
  const int E = in_sizes[9];
  const int B = out_size / D;
  float* outp = (float*)d_out;

  // workspace layout
  float*  h3f  = (float*)d_ws;                  // [N*D] f32 (layer-3 out)
  ushort* xb   = (ushort*)(h3f + (size_t)N * D); // [N*D] bf16 (x, then h1, h2)
  ushort* Abf  = xb + (size_t)N * D;            // [N*D] bf16 agg
  ushort* Wf   = Abf + (size_t)N * D;           // [3*2048*8] bf16 frag-layout W
  float*  outn = (float*)(Wf + 3 * 2048 * 8);   // [N]
  float*  innm = outn + N;                      // [N]
  int*    ocnt = (int*)(innm + N);              // [N]
  int*    icnt = ocnt + N;                      // [N]
  int*    cursor = icnt + N;                    // [N]
  int*    rowptr = cursor + N;                  // [N+1]
  int*    src_p  = rowptr + N + 1;              // [E]
  float*  coef_p = (float*)(src_p + E);         // [E]
  int*    bsum   = (int*)(coef_p + E);          // [nbs]
  int*    bptr   = bsum + ((N + 255) / 256);    // [nbs+1]

  const int eb  = (E + 255) / 256;
  const int nb  = (N + 255) / 256;
  const int nbs = (N + 255) / 256;
  const int gb  = (int)(((size_t)N * 16 + 255) / 256);
  const int mb  = (N + 63) / 64;
  const int cb  = (N * D / 8 + 255) / 256;

  // ---- CSR build + converts ----
  hipMemsetAsync(ocnt, 0, sizeof(int) * 3 * (size_t)N, stream);  // ocnt, icnt, cursor
  k_count<<<eb, 256, 0, stream>>>(src, dst, ocnt, icnt, E);
  k_norm<<<nb, 256, 0, stream>>>(ocnt, icnt, outn, innm, N);
  k_bsum<<<nbs, 256, 0, stream>>>(icnt, bsum, N);
  k_scan<<<1, 1024, 0, stream>>>(bsum, bptr, nbs);
  k_scan3<<<nbs, 256, 0, stream>>>(icnt, bptr, rowptr, N, nbs);
  k_place<<<eb, 256, 0, stream>>>(src, dst, (const float4*)w, outn, rowptr, cursor,
                                  src_p, coef_p, E);
  k_cvt<<<cb, 256, 0, stream>>>((const float4*)x, (uint4*)xb, N * D / 8);
  k_cvt_wf<<<8, 256, 0, stream>>>(W1, Wf);
  k_cvt_wf<<<8, 256, 0, stream>>>(W2, Wf + 16384);
  k_cvt_wf<<<8, 256, 0, stream>>>(W3, Wf + 32768);

  // ---- layer 1: xb -> Abf -> xb (bf16 h1) ----
  k_gather_bf<<<gb, 256, 0, stream>>>(xb, rowptr, src_p, coef_p, innm, Abf, N);
  k_gemm_mfma<<<mb, 256, 0, stream>>>(Abf, Wf, ln1g, ln1b, xb, N, 1);

  // ---- layer 2: xb -> Abf -> xb (bf16 h2) ----
  k_gather_bf<<<gb, 256, 0, stream>>>(xb, rowptr, src_p, coef_p, innm, Abf, N);
  k_gemm_mfma<<<mb, 256, 0, stream>>>(Abf, Wf + 16384, ln2g, ln2b, xb, N, 1);

  // ---- layer 3: xb -> Abf -> h3f (f32, no relu/ln) ----
  k_gather_bf<<<gb, 256, 0, stream>>>(xb, rowptr, src_p, coef_p, innm, Abf, N);
  k_gemm_mfma<<<mb, 256, 0, stream>>>(Abf, Wf + 32768, nullptr, nullptr, h3f, N, 0);

  // ---- readout ----
  k_readout<<<B, D, 0, stream>>>(h3f, gid, outp, N);
}

// Round 8
// 293.053 us; speedup vs baseline: 16.7270x; 1.1809x over previous
//
#include <hip/hip_runtime.h>

#define D 128
#define RS 16  // readout sub-blocks per graph
constexpr float EPS = 1e-5f;

typedef short bf16x8 __attribute__((ext_vector_type(8)));
typedef float f32x4 __attribute__((ext_vector_type(4)));

__device__ __forceinline__ uint f2bf(float f) {  // RNE f32->bf16 (finite inputs)
  union { float f; uint u; } v; v.f = f;
  return (v.u + 0x7fffu + ((v.u >> 16) & 1u)) >> 16;
}
__device__ __forceinline__ float bflo(uint u) {  // low bf16 of packed u32
  union { uint u; float f; } v; v.u = u << 16; return v.f;
}
__device__ __forceinline__ float bfhi(uint u) {  // high bf16
  union { uint u; float f; } v; v.u = u & 0xffff0000u; return v.f;
}

__device__ __forceinline__ int lower_bound(const int* __restrict__ a, int n, int key) {
  int lo = 0, hi = n;
  while (lo < hi) { int m = (lo + hi) >> 1; if (a[m] < key) lo = m + 1; else hi = m; }
  return lo;
}

// ---------- int degree counts ----------
__global__ void k_count(const int* __restrict__ src, const int* __restrict__ dst,
                        int* __restrict__ ocnt, int* __restrict__ icnt, int E) {
  int e = blockIdx.x * 256 + threadIdx.x;
  if (e < E) {
    atomicAdd(&ocnt[src[e]], 1);
    atomicAdd(&icnt[dst[e]], 1);
  }
}

// ---------- norms from int degrees ----------
__global__ void k_norm(const int* __restrict__ ocnt, const int* __restrict__ icnt,
                       float* __restrict__ outn, float* __restrict__ innm, int N) {
  int n = blockIdx.x * 256 + threadIdx.x;
  if (n < N) {
    outn[n] = rsqrtf(fmaxf((float)ocnt[n], 1.0f));
    innm[n] = rsqrtf(fmaxf((float)icnt[n], 1.0f));
  }
}

// ---------- scan level 1: per-block sums ----------
__global__ __launch_bounds__(256) void k_bsum(const int* __restrict__ cnt,
                                              int* __restrict__ bsum, int N) {
  int i = blockIdx.x * 256 + threadIdx.x;
  int v = (i < N) ? cnt[i] : 0;
#pragma unroll
  for (int off = 32; off; off >>= 1) v += __shfl_xor(v, off);
  __shared__ int ws[4];
  if ((threadIdx.x & 63) == 0) ws[threadIdx.x >> 6] = v;
  __syncthreads();
  if (threadIdx.x == 0) bsum[blockIdx.x] = ws[0] + ws[1] + ws[2] + ws[3];
}

// ---------- scan level 2: single-block exclusive scan ----------
__global__ __launch_bounds__(1024) void k_scan(const int* __restrict__ cnt,
                                               int* __restrict__ rowptr, int N) {
  __shared__ int part[1024];
  int t = threadIdx.x;
  int chunk = (N + 1023) / 1024;
  int beg = t * chunk, end = min(beg + chunk, N);
  int s = 0;
  for (int i = beg; i < end; ++i) s += cnt[i];
  part[t] = s;
  __syncthreads();
  for (int off = 1; off < 1024; off <<= 1) {
    int v = (t >= off) ? part[t - off] : 0;
    __syncthreads();
    part[t] += v;
    __syncthreads();
  }
  int excl = (t == 0) ? 0 : part[t - 1];
  for (int i = beg; i < end; ++i) { rowptr[i] = excl; excl += cnt[i]; }
  if (t == 0) rowptr[N] = part[1023];
}

// ---------- scan level 3: intra-block scan + block prefix ----------
__global__ __launch_bounds__(256) void k_scan3(const int* __restrict__ cnt,
                                               const int* __restrict__ bptr,
                                               int* __restrict__ rowptr, int N, int nbs) {
  int i = blockIdx.x * 256 + threadIdx.x;
  int lane = threadIdx.x & 63, wv = threadIdx.x >> 6;
  int orig = (i < N) ? cnt[i] : 0;
  int v = orig;
#pragma unroll
  for (int off = 1; off < 64; off <<= 1) {
    int t = __shfl_up(v, off);
    if (lane >= off) v += t;
  }
  __shared__ int wsum[4];
  if (lane == 63) wsum[wv] = v;
  __syncthreads();
  int woff = 0;
#pragma unroll
  for (int k = 0; k < 4; ++k)
    if (k < wv) woff += wsum[k];
  int excl = bptr[blockIdx.x] + woff + (v - orig);
  if (i < N) rowptr[i] = excl;
  if (blockIdx.x == 0 && threadIdx.x == 0) rowptr[N] = bptr[nbs];
}

// ---------- place edges into CSR; coef = mean(w)*out_norm[src] ----------
__global__ void k_place(const int* __restrict__ src, const int* __restrict__ dst,
                        const float4* __restrict__ w, const float* __restrict__ outn,
                        const int* __restrict__ rowptr, int* __restrict__ cursor,
                        int* __restrict__ src_p, float* __restrict__ coef_p, int E) {
  int e = blockIdx.x * 256 + threadIdx.x;
  if (e >= E) return;
  int d = dst[e];
  int p = rowptr[d] + atomicAdd(&cursor[d], 1);
  int s = src[e];
  float4 v = w[e];
  src_p[p] = s;
  coef_p[p] = (v.x + v.y + v.z + v.w) * 0.25f * outn[s];
}

// ---------- f32 -> bf16 bulk convert (8 elems/thread) ----------
__global__ void k_cvt(const float4* __restrict__ in, uint4* __restrict__ outp, int n8) {
  int i = blockIdx.x * 256 + threadIdx.x;
  if (i < n8) {
    float4 p = in[i * 2], q = in[i * 2 + 1];
    uint4 o;
    o.x = f2bf(p.x) | (f2bf(p.y) << 16);
    o.y = f2bf(p.z) | (f2bf(p.w) << 16);
    o.z = f2bf(q.x) | (f2bf(q.y) << 16);
    o.w = f2bf(q.z) | (f2bf(q.w) << 16);
    outp[i] = o;
  }
}

// ---------- W1/W2/W3 f32[128][128] -> bf16 MFMA B-fragment layout (all in one) ----------
// frag (ks,ct), lane l holds B[k][col]: k=ks*32+(l>>4)*8+j, col=ct*16+(l&15).
__global__ void k_cvt_wf(const float* __restrict__ W1, const float* __restrict__ W2,
                         const float* __restrict__ W3, ushort* __restrict__ Wf) {
  int tid = blockIdx.x * 256 + threadIdx.x;
  if (tid >= 3 * 2048) return;
  const float* Wsrc = (tid < 2048) ? W1 : (tid < 4096) ? W2 : W3;
  int t = tid & 2047;
  int lane = t & 63;
  int frag = t >> 6;              // 0..31
  int ks = frag >> 3, ct = frag & 7;
  int col = ct * 16 + (lane & 15);
  int kb = ks * 32 + (lane >> 4) * 8;
  uint p[8];
#pragma unroll
  for (int j = 0; j < 8; ++j) p[j] = f2bf(Wsrc[(kb + j) * D + col]);
  uint4 o;
  o.x = p[0] | (p[1] << 16);
  o.y = p[2] | (p[3] << 16);
  o.z = p[4] | (p[5] << 16);
  o.w = p[6] | (p[7] << 16);
  *(uint4*)(Wf + (size_t)tid * 8) = o;
}

// ---------- gather (bf16 h): agg[n] = bf16( innm[n] * sum coef*h[src] ) ----------
// 16 lanes/node, each lane owns 8 cols (16 B), fp32 accum, 4x unrolled.
__global__ __launch_bounds__(256) void k_gather_bf(
    const ushort* __restrict__ h, const int* __restrict__ rowptr,
    const int* __restrict__ src_p, const float* __restrict__ coef_p,
    const float* __restrict__ innm, ushort* __restrict__ agg, int N) {
  int idx = blockIdx.x * 256 + threadIdx.x;
  int n = idx >> 4, c = idx & 15;
  if (n >= N) return;
  int beg = rowptr[n], end = rowptr[n + 1];
  float a0 = 0, a1 = 0, a2 = 0, a3 = 0, a4 = 0, a5 = 0, a6 = 0, a7 = 0;
#define ACC8(q, f)                                        \
  a0 = fmaf(bflo(q.x), f, a0); a1 = fmaf(bfhi(q.x), f, a1); \
  a2 = fmaf(bflo(q.y), f, a2); a3 = fmaf(bfhi(q.y), f, a3); \
  a4 = fmaf(bflo(q.z), f, a4); a5 = fmaf(bfhi(q.z), f, a5); \
  a6 = fmaf(bflo(q.w), f, a6); a7 = fmaf(bfhi(q.w), f, a7);
  int j = beg;
  for (; j + 4 <= end; j += 4) {
    int s0 = src_p[j], s1 = src_p[j + 1], s2 = src_p[j + 2], s3 = src_p[j + 3];
    float f0 = coef_p[j], f1 = coef_p[j + 1], f2 = coef_p[j + 2], f3 = coef_p[j + 3];
    uint4 q0 = *(const uint4*)(h + (size_t)s0 * D + c * 8);
    uint4 q1 = *(const uint4*)(h + (size_t)s1 * D + c * 8);
    uint4 q2 = *(const uint4*)(h + (size_t)s2 * D + c * 8);
    uint4 q3 = *(const uint4*)(h + (size_t)s3 * D + c * 8);
    ACC8(q0, f0) ACC8(q1, f1) ACC8(q2, f2) ACC8(q3, f3)
  }
  for (; j < end; ++j) {
    int s = src_p[j];
    float f = coef_p[j];
    uint4 q = *(const uint4*)(h + (size_t)s * D + c * 8);
    ACC8(q, f)
  }
#undef ACC8
  float sc = innm[n];
  uint4 o;
  o.x = f2bf(a0 * sc) | (f2bf(a1 * sc) << 16);
  o.y = f2bf(a2 * sc) | (f2bf(a3 * sc) << 16);
  o.z = f2bf(a4 * sc) | (f2bf(a5 * sc) << 16);
  o.w = f2bf(a6 * sc) | (f2bf(a7 * sc) << 16);
  *(uint4*)(agg + (size_t)n * D + c * 8) = o;
}

// ---------- MFMA GEMM + fused ReLU+LN ----------
// 4 waves/block, wave owns 16 rows x 128 cols: 4 ksteps x 8 coltiles of
// mfma_f32_16x16x32_bf16. do_ln: bf16 out (via per-wave LDS transpose);
// else f32 out. LDS is wave-private slots of 16*D floats. No block barriers.
__global__ __launch_bounds__(256) void k_gemm_mfma(
    const ushort* __restrict__ agg, const ushort* __restrict__ Wf,
    const float* __restrict__ g, const float* __restrict__ bta,
    void* __restrict__ out, int N, int do_ln) {
  __shared__ float lds[4][16 * D];  // 32 KiB total: 8 KiB per wave
  const int lane = threadIdx.x & 63;
  const int wv = threadIdx.x >> 6;
  const int row0 = blockIdx.x * 64 + wv * 16;
  if (row0 >= N) return;
  const int lc = lane & 15, lg = lane >> 4;

  int arow = row0 + lc;
  if (arow > N - 1) arow = N - 1;
  const ushort* aptr = agg + (size_t)arow * D + lg * 8;

  f32x4 acc[8];
#pragma unroll
  for (int ct = 0; ct < 8; ++ct) acc[ct] = (f32x4){0.f, 0.f, 0.f, 0.f};

#pragma unroll
  for (int ks = 0; ks < 4; ++ks) {
    bf16x8 a = *(const bf16x8*)(aptr + ks * 32);
    const ushort* wp = Wf + ((size_t)(ks * 8) * 64 + lane) * 8;
#pragma unroll
    for (int ct = 0; ct < 8; ++ct) {
      bf16x8 b = *(const bf16x8*)(wp + ct * 512);
      acc[ct] = __builtin_amdgcn_mfma_f32_16x16x32_bf16(a, b, acc[ct], 0, 0, 0);
    }
  }

  if (do_ln) {
    float v[8][4];
#pragma unroll
    for (int ct = 0; ct < 8; ++ct)
#pragma unroll
      for (int j = 0; j < 4; ++j) v[ct][j] = fmaxf(acc[ct][j], 0.f);
    float mu[4], rs[4];
#pragma unroll
    for (int j = 0; j < 4; ++j) {
      float s = 0.f;
#pragma unroll
      for (int ct = 0; ct < 8; ++ct) s += v[ct][j];
#pragma unroll
      for (int off = 1; off < 16; off <<= 1) s += __shfl_xor(s, off);
      mu[j] = s * (1.0f / D);
    }
#pragma unroll
    for (int j = 0; j < 4; ++j) {
      float q = 0.f;
#pragma unroll
      for (int ct = 0; ct < 8; ++ct) {
        v[ct][j] -= mu[j];
        q = fmaf(v[ct][j], v[ct][j], q);
      }
#pragma unroll
      for (int off = 1; off < 16; off <<= 1) q += __shfl_xor(q, off);
      rs[j] = rsqrtf(q * (1.0f / D) + EPS);
    }
    ushort* lp = (ushort*)&lds[wv][0];  // 16x128 bf16 (half the 8 KiB slot)
#pragma unroll
    for (int ct = 0; ct < 8; ++ct) {
      float gc = g[ct * 16 + lc], bc = bta[ct * 16 + lc];
#pragma unroll
      for (int j = 0; j < 4; ++j)
        lp[(lg * 4 + j) * D + ct * 16 + lc] = (ushort)f2bf(fmaf(v[ct][j] * rs[j], gc, bc));
    }
    __builtin_amdgcn_wave_barrier();  // order LDS write->read (same wave)
    int r = row0 + (lane >> 2);  // lane copies 32 ushorts = quarter row
    if (r < N) {
      ushort* ob = (ushort*)out + (size_t)row0 * D + lane * 32;
#pragma unroll
      for (int i = 0; i < 4; ++i)
        ((uint4*)ob)[i] = ((const uint4*)(lp + lane * 32))[i];
    }
  } else {
    float* lp = &lds[wv][0];  // 16x128 f32 (full 8 KiB slot)
#pragma unroll
    for (int ct = 0; ct < 8; ++ct)
#pragma unroll
      for (int j = 0; j < 4; ++j)
        lp[(lg * 4 + j) * D + ct * 16 + lc] = acc[ct][j];
    __builtin_amdgcn_wave_barrier();  // order LDS write->read (same wave)
    int r = row0 + (lane >> 2);  // lane copies 32 floats = quarter row
    if (r < N) {
      float* ob = (float*)out + (size_t)row0 * D + lane * 32;
#pragma unroll
      for (int i = 0; i < 8; ++i)
        ((float4*)ob)[i] = ((const float4*)(lp + lane * 32))[i];
    }
  }
}

// ---------- readout stage 1: partial sums, RS blocks per graph ----------
__global__ __launch_bounds__(128) void k_rpart(
    const float* __restrict__ h, const int* __restrict__ gid,
    float* __restrict__ part, int N) {
  int b = blockIdx.x / RS, s = blockIdx.x % RS;
  int t = threadIdx.x;  // 128
  int start = lower_bound(gid, N, b);
  int end = lower_bound(gid, N, b + 1);
  int len = end - start;
  int chunk = (len + RS - 1) / RS;
  int rb = start + s * chunk;
  int re = min(rb + chunk, end);
  float acc = 0.f;
  for (int n = rb; n < re; ++n) acc += h[(size_t)n * D + t];
  part[((size_t)b * RS + s) * D + t] = acc;
}

// ---------- readout stage 2: reduce RS partials per graph ----------
__global__ __launch_bounds__(128) void k_rsum(
    const float* __restrict__ part, float* __restrict__ out) {
  int b = blockIdx.x;
  int t = threadIdx.x;
  float acc = 0.f;
#pragma unroll
  for (int s = 0; s < RS; ++s) acc += part[((size_t)b * RS + s) * D + t];
  out[(size_t)b * D + t] = acc;
}

extern "C" void kernel_launch(void* const* d_in, const int* in_sizes, int n_in,
                              void* d_out, int out_size, void* d_ws, size_t ws_size,
                              hipStream_t stream) {
  const float* x    = (const float*)d_in[0];
  const float* w    = (const float*)d_in[1];
  const float* W1   = (const float*)d_in[2];
  const float* W2   = (const float*)d_in[3];
  const float* W3   = (const float*)d_in[4];
  const float* ln1g = (const float*)d_in[5];
  const float* ln1b = (const float*)d_in[6];
  const float* ln2g = (const float*)d_in[7];
  const float* ln2b = (const float*)d_in[8];
  const int* src = (const int*)d_in[9];
  const int* dst = (const int*)d_in[10];
  const int* gid = (const int*)d_in[11];
  const int N = in_sizes[0] / D;
  const int E = in_sizes[9];
  const int B = out_size / D;
  float* outp = (float*)d_out;

  // workspace layout
  float*  h3f  = (float*)d_ws;                   // [N*D] f32 (layer-3 out)
  ushort* xb   = (ushort*)(h3f + (size_t)N * D); // [N*D] bf16 (x, then h1, h2)
  ushort* Abf  = xb + (size_t)N * D;             // [N*D] bf16 agg
  ushort* Wf   = Abf + (size_t)N * D;            // [3*2048*8] bf16 frag-layout W
  float*  outn = (float*)(Wf + 3 * 2048 * 8);    // [N]
  float*  innm = outn + N;                       // [N]
  int*    ocnt = (int*)(innm + N);               // [N]
  int*    icnt = ocnt + N;                       // [N]
  int*    cursor = icnt + N;                     // [N]
  int*    rowptr = cursor + N;                   // [N+1]
  int*    src_p  = rowptr + N + 1;               // [E]
  float*  coef_p = (float*)(src_p + E);          // [E]
  int*    bsum   = (int*)(coef_p + E);           // [nbs]
  int*    bptr   = bsum + ((N + 255) / 256);     // [nbs+1]
  float*  part   = (float*)(bptr + (N + 255) / 256 + 1);  // [B*RS*D]

  const int eb  = (E + 255) / 256;
  const int nb  = (N + 255) / 256;
  const int nbs = (N + 255) / 256;
  const int gb  = (int)(((size_t)N * 16 + 255) / 256);
  const int mb  = (N + 63) / 64;
  const int cb  = (N * D / 8 + 255) / 256;

  // ---- CSR build + converts ----
  hipMemsetAsync(ocnt, 0, sizeof(int) * 3 * (size_t)N, stream);  // ocnt, icnt, cursor
  k_count<<<eb, 256, 0, stream>>>(src, dst, ocnt, icnt, E);
  k_norm<<<nb, 256, 0, stream>>>(ocnt, icnt, outn, innm, N);
  k_bsum<<<nbs, 256, 0, stream>>>(icnt, bsum, N);
  k_scan<<<1, 1024, 0, stream>>>(bsum, bptr, nbs);
  k_scan3<<<nbs, 256, 0, stream>>>(icnt, bptr, rowptr, N, nbs);
  k_place<<<eb, 256, 0, stream>>>(src, dst, (const float4*)w, outn, rowptr, cursor,
                                  src_p, coef_p, E);
  k_cvt<<<cb, 256, 0, stream>>>((const float4*)x, (uint4*)xb, N * D / 8);
  k_cvt_wf<<<24, 256, 0, stream>>>(W1, W2, W3, Wf);

  // ---- layer 1: xb -> Abf -> xb (bf16 h1) ----
  k_gather_bf<<<gb, 256, 0, stream>>>(xb, rowptr, src_p, coef_p, innm, Abf, N);
  k_gemm_mfma<<<mb, 256, 0, stream>>>(Abf, Wf, ln1g, ln1b, xb, N, 1);

  // ---- layer 2: xb -> Abf -> xb (bf16 h2) ----
  k_gather_bf<<<gb, 256, 0, stream>>>(xb, rowptr, src_p, coef_p, innm, Abf, N);
  k_gemm_mfma<<<mb, 256, 0, stream>>>(Abf, Wf + 16384, ln2g, ln2b, xb, N, 1);

  // ---- layer 3: xb -> Abf -> h3f (f32, no relu/ln) ----
  k_gather_bf<<<gb, 256, 0, stream>>>(xb, rowptr, src_p, coef_p, innm, Abf, N);
  k_gemm_mfma<<<mb, 256, 0, stream>>>(Abf, Wf + 32768, nullptr, nullptr, h3f, N, 0);

  // ---- readout (two-stage, deterministic) ----
  k_rpart<<<B * RS, 128, 0, stream>>>(h3f, gid, part, N);
  k_rsum<<<B, 128, 0, stream>>>(part, outp);
}

// Round 9
// 268.829 us; speedup vs baseline: 18.2342x; 1.0901x over previous
//
#include <hip/hip_runtime.h>

#define D 128
#define RS 16  // readout sub-blocks per graph
constexpr float EPS = 1e-5f;

typedef short bf16x8 __attribute__((ext_vector_type(8)));
typedef float f32x4 __attribute__((ext_vector_type(4)));

__device__ __forceinline__ uint f2bf(float f) {  // RNE f32->bf16 (finite inputs)
  union { float f; uint u; } v; v.f = f;
  return (v.u + 0x7fffu + ((v.u >> 16) & 1u)) >> 16;
}
__device__ __forceinline__ float bflo(uint u) {  // low bf16 of packed u32
  union { uint u; float f; } v; v.u = u << 16; return v.f;
}
__device__ __forceinline__ float bfhi(uint u) {  // high bf16
  union { uint u; float f; } v; v.u = u & 0xffff0000u; return v.f;
}

__device__ __forceinline__ int lower_bound(const int* __restrict__ a, int n, int key) {
  int lo = 0, hi = n;
  while (lo < hi) { int m = (lo + hi) >> 1; if (a[m] < key) lo = m + 1; else hi = m; }
  return lo;
}

// ---------- fused preprocessing: degree counts | x->bf16 | W->frag layout ----------
// count is memory-side-atomic bound (~24 G RMW/s); the convert blocks ride the
// idle HBM/L2 bandwidth underneath it.
__global__ __launch_bounds__(256) void k_pre(
    const int* __restrict__ src, const int* __restrict__ dst,
    int* __restrict__ ocnt, int* __restrict__ icnt, int E,
    const float4* __restrict__ x, uint4* __restrict__ xb, int n8,
    const float* __restrict__ W1, const float* __restrict__ W2,
    const float* __restrict__ W3, ushort* __restrict__ Wf,
    int eb, int cb) {
  int bid = blockIdx.x;
  if (bid < eb) {
    int e = bid * 256 + threadIdx.x;
    if (e < E) {
      atomicAdd(&ocnt[src[e]], 1);
      atomicAdd(&icnt[dst[e]], 1);
    }
  } else if (bid < eb + cb) {
    int i = (bid - eb) * 256 + threadIdx.x;
    if (i < n8) {
      float4 p = x[i * 2], q = x[i * 2 + 1];
      uint4 o;
      o.x = f2bf(p.x) | (f2bf(p.y) << 16);
      o.y = f2bf(p.z) | (f2bf(p.w) << 16);
      o.z = f2bf(q.x) | (f2bf(q.y) << 16);
      o.w = f2bf(q.z) | (f2bf(q.w) << 16);
      xb[i] = o;
    }
  } else {
    // W1/W2/W3 f32[128][128] -> bf16 MFMA B-fragment layout.
    // frag (ks,ct), lane l holds B[k][col]: k=ks*32+(l>>4)*8+j, col=ct*16+(l&15).
    int tid = (bid - eb - cb) * 256 + threadIdx.x;
    if (tid < 3 * 2048) {
      const float* Wsrc = (tid < 2048) ? W1 : (tid < 4096) ? W2 : W3;
      int t = tid & 2047;
      int lane = t & 63;
      int frag = t >> 6;  // 0..31
      int ks = frag >> 3, ct = frag & 7;
      int col = ct * 16 + (lane & 15);
      int kb = ks * 32 + (lane >> 4) * 8;
      uint p[8];
#pragma unroll
      for (int j = 0; j < 8; ++j) p[j] = f2bf(Wsrc[(kb + j) * D + col]);
      uint4 o;
      o.x = p[0] | (p[1] << 16);
      o.y = p[2] | (p[3] << 16);
      o.z = p[4] | (p[5] << 16);
      o.w = p[6] | (p[7] << 16);
      *(uint4*)(Wf + (size_t)tid * 8) = o;
    }
  }
}

// ---------- norms + per-block icnt sums (scan level 1) ----------
__global__ __launch_bounds__(256) void k_norm_bsum(
    const int* __restrict__ ocnt, const int* __restrict__ icnt,
    float* __restrict__ outn, float* __restrict__ innm,
    int* __restrict__ bsum, int N) {
  int i = blockIdx.x * 256 + threadIdx.x;
  int ic = 0;
  if (i < N) {
    ic = icnt[i];
    outn[i] = rsqrtf(fmaxf((float)ocnt[i], 1.0f));
    innm[i] = rsqrtf(fmaxf((float)ic, 1.0f));
  }
  int v = ic;
#pragma unroll
  for (int off = 32; off; off >>= 1) v += __shfl_xor(v, off);
  __shared__ int ws[4];
  if ((threadIdx.x & 63) == 0) ws[threadIdx.x >> 6] = v;
  __syncthreads();
  if (threadIdx.x == 0) bsum[blockIdx.x] = ws[0] + ws[1] + ws[2] + ws[3];
}

// ---------- scan level 2: single-block exclusive scan ----------
__global__ __launch_bounds__(1024) void k_scan(const int* __restrict__ cnt,
                                               int* __restrict__ rowptr, int N) {
  __shared__ int part[1024];
  int t = threadIdx.x;
  int chunk = (N + 1023) / 1024;
  int beg = t * chunk, end = min(beg + chunk, N);
  int s = 0;
  for (int i = beg; i < end; ++i) s += cnt[i];
  part[t] = s;
  __syncthreads();
  for (int off = 1; off < 1024; off <<= 1) {
    int v = (t >= off) ? part[t - off] : 0;
    __syncthreads();
    part[t] += v;
    __syncthreads();
  }
  int excl = (t == 0) ? 0 : part[t - 1];
  for (int i = beg; i < end; ++i) { rowptr[i] = excl; excl += cnt[i]; }
  if (t == 0) rowptr[N] = part[1023];
}

// ---------- scan level 3: intra-block scan + block prefix ----------
__global__ __launch_bounds__(256) void k_scan3(const int* __restrict__ cnt,
                                               const int* __restrict__ bptr,
                                               int* __restrict__ rowptr, int N, int nbs) {
  int i = blockIdx.x * 256 + threadIdx.x;
  int lane = threadIdx.x & 63, wv = threadIdx.x >> 6;
  int orig = (i < N) ? cnt[i] : 0;
  int v = orig;
#pragma unroll
  for (int off = 1; off < 64; off <<= 1) {
    int t = __shfl_up(v, off);
    if (lane >= off) v += t;
  }
  __shared__ int wsum[4];
  if (lane == 63) wsum[wv] = v;
  __syncthreads();
  int woff = 0;
#pragma unroll
  for (int k = 0; k < 4; ++k)
    if (k < wv) woff += wsum[k];
  int excl = bptr[blockIdx.x] + woff + (v - orig);
  if (i < N) rowptr[i] = excl;
  if (blockIdx.x == 0 && threadIdx.x == 0) rowptr[N] = bptr[nbs];
}

// ---------- place edges into CSR; coef = mean(w)*out_norm[src] ----------
__global__ void k_place(const int* __restrict__ src, const int* __restrict__ dst,
                        const float4* __restrict__ w, const float* __restrict__ outn,
                        const int* __restrict__ rowptr, int* __restrict__ cursor,
                        int* __restrict__ src_p, float* __restrict__ coef_p, int E) {
  int e = blockIdx.x * 256 + threadIdx.x;
  if (e >= E) return;
  int d = dst[e];
  int p = rowptr[d] + atomicAdd(&cursor[d], 1);
  int s = src[e];
  float4 v = w[e];
  src_p[p] = s;
  coef_p[p] = (v.x + v.y + v.z + v.w) * 0.25f * outn[s];
}

// ---------- FUSED layer: gather -> MFMA GEMM -> (ReLU+LN | f32 out) ----------
// 4 waves/block, wave owns 16 output rows. Phase A: wave gathers its 16 rows
// (bf16, in_norm folded) into a wave-private padded LDS tile [16][136] ushorts.
// Phase B: A-fragments read from LDS, 4 ksteps x 8 coltiles of
// mfma_f32_16x16x32_bf16, then the LN/f32 epilogue (reusing the LDS slot).
// LDS strictly wave-private -> no block barriers; tail waves may return early.
__global__ __launch_bounds__(256) void k_fused(
    const ushort* __restrict__ h, const int* __restrict__ rowptr,
    const int* __restrict__ src_p, const float* __restrict__ coef_p,
    const float* __restrict__ innm, const ushort* __restrict__ Wf,
    const float* __restrict__ g, const float* __restrict__ bta,
    void* __restrict__ out, int N, int do_ln) {
  __shared__ float lds[4][16 * D];  // 32 KiB: 8 KiB per wave (A-tile, then epilogue)
  const int lane = threadIdx.x & 63;
  const int wv = threadIdx.x >> 6;
  const int row0 = blockIdx.x * 64 + wv * 16;
  if (row0 >= N) return;

  // ---- phase A: gather 16 rows into LDS tile [16][136] (pad -> 2-way banks only)
  ushort* at = (ushort*)&lds[wv][0];
  {
    const int grp = lane >> 4;  // 4 groups of 16 lanes
    const int c = lane & 15;    // lane's col-octet (8 bf16 = 16 B)
    for (int rr = 0; rr < 4; ++rr) {
      int n = row0 + grp * 4 + rr;  // uniform within group
      if (n >= N) break;
      int beg = rowptr[n], end = rowptr[n + 1];
      float a0 = 0, a1 = 0, a2 = 0, a3 = 0, a4 = 0, a5 = 0, a6 = 0, a7 = 0;
#define ACC8(q, f)                                          \
  a0 = fmaf(bflo(q.x), f, a0); a1 = fmaf(bfhi(q.x), f, a1); \
  a2 = fmaf(bflo(q.y), f, a2); a3 = fmaf(bfhi(q.y), f, a3); \
  a4 = fmaf(bflo(q.z), f, a4); a5 = fmaf(bfhi(q.z), f, a5); \
  a6 = fmaf(bflo(q.w), f, a6); a7 = fmaf(bfhi(q.w), f, a7);
      int j = beg;
      for (; j + 4 <= end; j += 4) {
        int s0 = src_p[j], s1 = src_p[j + 1], s2 = src_p[j + 2], s3 = src_p[j + 3];
        float f0 = coef_p[j], f1 = coef_p[j + 1], f2 = coef_p[j + 2], f3 = coef_p[j + 3];
        uint4 q0 = *(const uint4*)(h + (size_t)s0 * D + c * 8);
        uint4 q1 = *(const uint4*)(h + (size_t)s1 * D + c * 8);
        uint4 q2 = *(const uint4*)(h + (size_t)s2 * D + c * 8);
        uint4 q3 = *(const uint4*)(h + (size_t)s3 * D + c * 8);
        ACC8(q0, f0) ACC8(q1, f1) ACC8(q2, f2) ACC8(q3, f3)
      }
      for (; j < end; ++j) {
        int s = src_p[j];
        float f = coef_p[j];
        uint4 q = *(const uint4*)(h + (size_t)s * D + c * 8);
        ACC8(q, f)
      }
#undef ACC8
      float sc = innm[n];
      uint4 o;
      o.x = f2bf(a0 * sc) | (f2bf(a1 * sc) << 16);
      o.y = f2bf(a2 * sc) | (f2bf(a3 * sc) << 16);
      o.z = f2bf(a4 * sc) | (f2bf(a5 * sc) << 16);
      o.w = f2bf(a6 * sc) | (f2bf(a7 * sc) << 16);
      *(uint4*)(at + (grp * 4 + rr) * 136 + c * 8) = o;
    }
  }
  // LDS ops are in-order per wave; fence compiler reordering + drain writes.
  asm volatile("s_waitcnt lgkmcnt(0)" ::: "memory");
  __builtin_amdgcn_sched_barrier(0);

  // ---- phase B: MFMA from LDS A-tile
  const int lc = lane & 15, lg = lane >> 4;
  f32x4 acc[8];
#pragma unroll
  for (int ct = 0; ct < 8; ++ct) acc[ct] = (f32x4){0.f, 0.f, 0.f, 0.f};
#pragma unroll
  for (int ks = 0; ks < 4; ++ks) {
    bf16x8 a = *(const bf16x8*)(at + lc * 136 + ks * 32 + lg * 8);
    const ushort* wp = Wf + ((size_t)(ks * 8) * 64 + lane) * 8;
#pragma unroll
    for (int ct = 0; ct < 8; ++ct) {
      bf16x8 b = *(const bf16x8*)(wp + ct * 512);
      acc[ct] = __builtin_amdgcn_mfma_f32_16x16x32_bf16(a, b, acc[ct], 0, 0, 0);
    }
  }
  asm volatile("s_waitcnt lgkmcnt(0)" ::: "memory");  // A-tile dead; slot reused below
  __builtin_amdgcn_sched_barrier(0);

  if (do_ln) {
    float v[8][4];
#pragma unroll
    for (int ct = 0; ct < 8; ++ct)
#pragma unroll
      for (int j = 0; j < 4; ++j) v[ct][j] = fmaxf(acc[ct][j], 0.f);
    float mu[4], rs[4];
#pragma unroll
    for (int j = 0; j < 4; ++j) {
      float s = 0.f;
#pragma unroll
      for (int ct = 0; ct < 8; ++ct) s += v[ct][j];
#pragma unroll
      for (int off = 1; off < 16; off <<= 1) s += __shfl_xor(s, off);
      mu[j] = s * (1.0f / D);
    }
#pragma unroll
    for (int j = 0; j < 4; ++j) {
      float q = 0.f;
#pragma unroll
      for (int ct = 0; ct < 8; ++ct) {
        v[ct][j] -= mu[j];
        q = fmaf(v[ct][j], v[ct][j], q);
      }
#pragma unroll
      for (int off = 1; off < 16; off <<= 1) q += __shfl_xor(q, off);
      rs[j] = rsqrtf(q * (1.0f / D) + EPS);
    }
    ushort* lp = (ushort*)&lds[wv][0];  // 16x128 bf16 (half the slot)
#pragma unroll
    for (int ct = 0; ct < 8; ++ct) {
      float gc = g[ct * 16 + lc], bc = bta[ct * 16 + lc];
#pragma unroll
      for (int j = 0; j < 4; ++j)
        lp[(lg * 4 + j) * D + ct * 16 + lc] = (ushort)f2bf(fmaf(v[ct][j] * rs[j], gc, bc));
    }
    __builtin_amdgcn_wave_barrier();
    int r = row0 + (lane >> 2);  // lane copies 32 ushorts = quarter row
    if (r < N) {
      ushort* ob = (ushort*)out + (size_t)row0 * D + lane * 32;
#pragma unroll
      for (int i = 0; i < 4; ++i)
        ((uint4*)ob)[i] = ((const uint4*)(lp + lane * 32))[i];
    }
  } else {
    float* lp = &lds[wv][0];  // 16x128 f32 (full 8 KiB slot)
#pragma unroll
    for (int ct = 0; ct < 8; ++ct)
#pragma unroll
      for (int j = 0; j < 4; ++j)
        lp[(lg * 4 + j) * D + ct * 16 + lc] = acc[ct][j];
    __builtin_amdgcn_wave_barrier();
    int r = row0 + (lane >> 2);  // lane copies 32 floats = quarter row
    if (r < N) {
      float* ob = (float*)out + (size_t)row0 * D + lane * 32;
#pragma unroll
      for (int i = 0; i < 8; ++i)
        ((float4*)ob)[i] = ((const float4*)(lp + lane * 32))[i];
    }
  }
}

// ---------- readout stage 1: partial sums, RS blocks per graph ----------
__global__ __launch_bounds__(128) void k_rpart(
    const float* __restrict__ h, const int* __restrict__ gid,
    float* __restrict__ part, int N) {
  int b = blockIdx.x / RS, s = blockIdx.x % RS;
  int t = threadIdx.x;  // 128
  int start = lower_bound(gid, N, b);
  int end = lower_bound(gid, N, b + 1);
  int len = end - start;
  int chunk = (len + RS - 1) / RS;
  int rb = start + s * chunk;
  int re = min(rb + chunk, end);
  float acc = 0.f;
  for (int n = rb; n < re; ++n) acc += h[(size_t)n * D + t];
  part[((size_t)b * RS + s) * D + t] = acc;
}

// ---------- readout stage 2: reduce RS partials per graph ----------
__global__ __launch_bounds__(128) void k_rsum(
    const float* __restrict__ part, float* __restrict__ out) {
  int b = blockIdx.x;
  int t = threadIdx.x;
  float acc = 0.f;
#pragma unroll
  for (int s = 0; s < RS; ++s) acc += part[((size_t)b * RS + s) * D + t];
  out[(size_t)b * D + t] = acc;
}

extern "C" void kernel_launch(void* const* d_in, const int* in_sizes, int n_in,
                              void* d_out, int out_size, void* d_ws, size_t ws_size,
                              hipStream_t stream) {
  const float* x    = (const float*)d_in[0];
  const float* w    = (const float*)d_in[1];
  const float* W1   = (const float*)d_in[2];
  const float* W2   = (const float*)d_in[3];
  const float* W3   = (const float*)d_in[4];
  const float* ln1g = (const float*)d_in[5];
  const float* ln1b = (const float*)d_in[6];
  const float* ln2g = (const float*)d_in[7];
  const float* ln2b = (const float*)d_in[8];
  const int* src = (const int*)d_in[9];
  const int* dst = (const int*)d_in[10];
  const int* gid = (const int*)d_in[11];
  const int N = in_sizes[0] / D;
  const int E = in_sizes[9];
  const int B = out_size / D;
  float* outp = (float*)d_out;

  // workspace layout
  float*  h3f  = (float*)d_ws;                   // [N*D] f32 (layer-3 out)
  ushort* xb   = (ushort*)(h3f + (size_t)N * D); // [N*D] bf16 (x, then h2)
  ushort* hb1  = xb + (size_t)N * D;             // [N*D] bf16 (h1)
  ushort* Wf   = hb1 + (size_t)N * D;            // [3*2048*8] bf16 frag-layout W
  float*  outn = (float*)(Wf + 3 * 2048 * 8);    // [N]
  float*  innm = outn + N;                       // [N]
  int*    ocnt = (int*)(innm + N);               // [N]
  int*    icnt = ocnt + N;                       // [N]
  int*    cursor = icnt + N;                     // [N]
  int*    rowptr = cursor + N;                   // [N+1]
  int*    src_p  = rowptr + N + 1;               // [E]
  float*  coef_p = (float*)(src_p + E);          // [E]
  int*    bsum   = (int*)(coef_p + E);           // [nbs]
  int*    bptr   = bsum + ((N + 255) / 256);     // [nbs+1]
  float*  part   = (float*)(bptr + (N + 255) / 256 + 1);  // [B*RS*D]

  const int eb  = (E + 255) / 256;
  const int nbs = (N + 255) / 256;
  const int mb  = (N + 63) / 64;
  const int n8  = N * D / 8;
  const int cb  = (n8 + 255) / 256;

  // ---- CSR build + converts (converts overlap the atomic-bound count) ----
  hipMemsetAsync(ocnt, 0, sizeof(int) * 3 * (size_t)N, stream);  // ocnt, icnt, cursor
  k_pre<<<eb + cb + 24, 256, 0, stream>>>(src, dst, ocnt, icnt, E,
                                          (const float4*)x, (uint4*)xb, n8,
                                          W1, W2, W3, Wf, eb, cb);
  k_norm_bsum<<<nbs, 256, 0, stream>>>(ocnt, icnt, outn, innm, bsum, N);
  k_scan<<<1, 1024, 0, stream>>>(bsum, bptr, nbs);
  k_scan3<<<nbs, 256, 0, stream>>>(icnt, bptr, rowptr, N, nbs);
  k_place<<<eb, 256, 0, stream>>>(src, dst, (const float4*)w, outn, rowptr, cursor,
                                  src_p, coef_p, E);

  // ---- 3 fused layers: gather+GEMM+LN in one kernel each ----
  k_fused<<<mb, 256, 0, stream>>>(xb, rowptr, src_p, coef_p, innm, Wf,
                                  ln1g, ln1b, hb1, N, 1);
  k_fused<<<mb, 256, 0, stream>>>(hb1, rowptr, src_p, coef_p, innm, Wf + 16384,
                                  ln2g, ln2b, xb, N, 1);
  k_fused<<<mb, 256, 0, stream>>>(xb, rowptr, src_p, coef_p, innm, Wf + 32768,
                                  nullptr, nullptr, h3f, N, 0);

  // ---- readout (two-stage, deterministic) ----
  k_rpart<<<B * RS, 128, 0, stream>>>(h3f, gid, part, N);
  k_rsum<<<B, 128, 0, stream>>>(part, outp);
}